// Round 5
// baseline (369.429 us; speedup 1.0000x reference)
//
#include <hip/hip_runtime.h>
#include <hip/hip_bf16.h>
#include <math.h>

#define N 1024
#define F 256
#define H 64

typedef __attribute__((ext_vector_type(8))) short bf16x8;
typedef __attribute__((ext_vector_type(4))) float f32x4;

__device__ __forceinline__ float wave_reduce_sum(float v) {
#pragma unroll
  for (int off = 32; off; off >>= 1) v += __shfl_xor(v, off, 64);
  return v;
}

__device__ __forceinline__ short bfc(float x) {
  __hip_bfloat16 h = __float2bfloat16(x);
  return __builtin_bit_cast(short, h);
}

__device__ __forceinline__ unsigned int bfpack(float a, float b) {
  return (unsigned int)(unsigned short)bfc(a) | ((unsigned int)(unsigned short)bfc(b) << 16);
}

// ---------------- FUSED input_proj + qkv: Linear->LN->ReLU->Linear->ReLU->qkv proj
__global__ void k_input_qkv(const float* __restrict__ feat,
                            const float* __restrict__ w1, const float* __restrict__ b1,
                            const float* __restrict__ lng, const float* __restrict__ lnb,
                            const float* __restrict__ w2, const float* __restrict__ b2,
                            const float* __restrict__ aw, const float* __restrict__ abias,
                            float* __restrict__ h, float* __restrict__ Qh,
                            float* __restrict__ Kh, float* __restrict__ Vh) {
  const int row = blockIdx.x;
  const int lane = threadIdx.x;  // 0..63
  __shared__ float frow[F];
#pragma unroll
  for (int c = 0; c < 4; ++c) frow[c * 64 + lane] = feat[row * F + c * 64 + lane];
  __syncthreads();
  float acc = b1[lane];
#pragma unroll 8
  for (int k = 0; k < F; ++k) acc += frow[k] * w1[k * H + lane];
  float mu = wave_reduce_sum(acc) * (1.f / 64.f);
  float d = acc - mu;
  float var = wave_reduce_sum(d * d) * (1.f / 64.f);
  float y = d * rsqrtf(var + 1e-5f) * lng[lane] + lnb[lane];
  y = fmaxf(y, 0.f);
  __shared__ float yrow[H];
  yrow[lane] = y;
  __syncthreads();
  float acc2 = b2[lane];
#pragma unroll 8
  for (int k = 0; k < H; ++k) acc2 += yrow[k] * w2[k * H + lane];
  float hv = fmaxf(acc2, 0.f);
  h[row * H + lane] = hv;
  __shared__ float hrow[H];
  hrow[lane] = hv;
  __syncthreads();
  float a0 = abias[lane], a1 = abias[64 + lane], a2 = abias[128 + lane];
#pragma unroll 8
  for (int k = 0; k < H; ++k) {
    float hk = hrow[k];
    a0 += hk * aw[k * 192 + lane];
    a1 += hk * aw[k * 192 + 64 + lane];
    a2 += hk * aw[k * 192 + 128 + lane];
  }
  const int base = (lane >> 4) * (N * 16) + row * 16 + (lane & 15);
  Qh[base] = a0;
  Kh[base] = a1;
  Vh[base] = a2;
}

// ---------------- attention v2: thread = (q-row, j-slot), private online softmax.
__global__ __launch_bounds__(256) void k_attn2(const float* __restrict__ Qh,
                                               const float* __restrict__ Kh,
                                               const float* __restrict__ Vh,
                                               float* __restrict__ o) {
  const int head = blockIdx.x >> 7;
  const int i0 = (blockIdx.x & 127) * 8;
  const int tid = threadIdx.x;
  const int q8 = tid >> 5, js = tid & 31;
  const int i = i0 + q8;

  const float* qp = Qh + head * (N * 16) + i * 16;
  const float4 q0 = *(const float4*)(qp);
  const float4 q1 = *(const float4*)(qp + 4);
  const float4 q2 = *(const float4*)(qp + 8);
  const float4 q3 = *(const float4*)(qp + 12);
  const float* kb = Kh + head * (N * 16);
  const float* vb = Vh + head * (N * 16);

  float m = -3.0e38f, s = 0.f;
  float4 c0 = {0, 0, 0, 0}, c1 = {0, 0, 0, 0}, c2 = {0, 0, 0, 0}, c3 = {0, 0, 0, 0};

  int j = js;
  const float* kp = kb + j * 16;
  const float* vp = vb + j * 16;
  float4 k0 = *(const float4*)(kp), k1 = *(const float4*)(kp + 4);
  float4 k2 = *(const float4*)(kp + 8), k3 = *(const float4*)(kp + 12);
  float4 v0 = *(const float4*)(vp), v1 = *(const float4*)(vp + 4);
  float4 v2 = *(const float4*)(vp + 8), v3 = *(const float4*)(vp + 12);

#pragma unroll 1
  for (int t = 0; t < 32; ++t) {
    const int jn = (j + 32) & (N - 1);  // last-iter wrap: in-bounds, result unused
    const float* kpn = kb + jn * 16;
    const float* vpn = vb + jn * 16;
    float4 nk0 = *(const float4*)(kpn), nk1 = *(const float4*)(kpn + 4);
    float4 nk2 = *(const float4*)(kpn + 8), nk3 = *(const float4*)(kpn + 12);
    float4 nv0 = *(const float4*)(vpn), nv1 = *(const float4*)(vpn + 4);
    float4 nv2 = *(const float4*)(vpn + 8), nv3 = *(const float4*)(vpn + 12);

    float sc = q0.x * k0.x + q0.y * k0.y + q0.z * k0.z + q0.w * k0.w;
    sc += q1.x * k1.x + q1.y * k1.y + q1.z * k1.z + q1.w * k1.w;
    sc += q2.x * k2.x + q2.y * k2.y + q2.z * k2.z + q2.w * k2.w;
    sc += q3.x * k3.x + q3.y * k3.y + q3.z * k3.z + q3.w * k3.w;
    sc *= 0.25f;  // 1/sqrt(16)

    float mn = fmaxf(m, sc);
    float cc = __expf(m - mn);
    float p = __expf(sc - mn);
    s = s * cc + p;
    m = mn;
    c0.x = c0.x * cc + p * v0.x; c0.y = c0.y * cc + p * v0.y;
    c0.z = c0.z * cc + p * v0.z; c0.w = c0.w * cc + p * v0.w;
    c1.x = c1.x * cc + p * v1.x; c1.y = c1.y * cc + p * v1.y;
    c1.z = c1.z * cc + p * v1.z; c1.w = c1.w * cc + p * v1.w;
    c2.x = c2.x * cc + p * v2.x; c2.y = c2.y * cc + p * v2.y;
    c2.z = c2.z * cc + p * v2.z; c2.w = c2.w * cc + p * v2.w;
    c3.x = c3.x * cc + p * v3.x; c3.y = c3.y * cc + p * v3.y;
    c3.z = c3.z * cc + p * v3.z; c3.w = c3.w * cc + p * v3.w;

    k0 = nk0; k1 = nk1; k2 = nk2; k3 = nk3;
    v0 = nv0; v1 = nv1; v2 = nv2; v3 = nv3;
    j = jn;
  }

  float M = m, S = s;
#pragma unroll
  for (int off = 16; off; off >>= 1) {
    float Mo = __shfl_xor(M, off, 64);
    float So = __shfl_xor(S, off, 64);
    float Mn = fmaxf(M, Mo);
    S = S * __expf(M - Mn) + So * __expf(Mo - Mn);
    M = Mn;
  }
  const float wgt = __expf(m - M) / S;

  __shared__ float lds[8][32][17];
  float* lp = &lds[q8][js][0];
  lp[0] = c0.x * wgt;  lp[1] = c0.y * wgt;  lp[2] = c0.z * wgt;  lp[3] = c0.w * wgt;
  lp[4] = c1.x * wgt;  lp[5] = c1.y * wgt;  lp[6] = c1.z * wgt;  lp[7] = c1.w * wgt;
  lp[8] = c2.x * wgt;  lp[9] = c2.y * wgt;  lp[10] = c2.z * wgt; lp[11] = c2.w * wgt;
  lp[12] = c3.x * wgt; lp[13] = c3.y * wgt; lp[14] = c3.z * wgt; lp[15] = c3.w * wgt;
  __syncthreads();

  if (tid < 128) {
    const int q = tid >> 4, d = tid & 15;
    float sum = 0.f;
#pragma unroll
    for (int k = 0; k < 32; ++k) sum += lds[q][k][d];
    o[(i0 + q) * H + head * 16 + d] = sum;
  }
}

// ---------------- attn out proj + residual + LN -> enc
__global__ void k_attn_out(const float* __restrict__ o, const float* __restrict__ w,
                           const float* __restrict__ b, const float* __restrict__ h,
                           const float* __restrict__ lng, const float* __restrict__ lnb,
                           float* __restrict__ enc) {
  const int row = blockIdx.x;
  const int lane = threadIdx.x;
  __shared__ float orow[H];
  orow[lane] = o[row * H + lane];
  __syncthreads();
  float a = b[lane];
#pragma unroll 8
  for (int k = 0; k < H; ++k) a += orow[k] * w[k * H + lane];
  float x = h[row * H + lane] + a;
  float mu = wave_reduce_sum(x) * (1.f / 64.f);
  float d = x - mu;
  float var = wave_reduce_sum(d * d) * (1.f / 64.f);
  enc[row * H + lane] = d * rsqrtf(var + 1e-5f) * lng[lane] + lnb[lane];
}

// ---------------- MERGED prep: blocks 0..15 = combos; blocks 16..19 = W4^T MFMA frags
__global__ __launch_bounds__(256) void k_prep(const float* __restrict__ pg1,
                                              const float* __restrict__ pv1,
                                              float* __restrict__ WgA, float* __restrict__ WgB,
                                              float* __restrict__ WvA, float* __restrict__ WvB,
                                              unsigned int* __restrict__ WF) {
  const int blk = blockIdx.x;
  if (blk < 16) {
    int idx = blk * 256 + threadIdx.x;  // 0..4095 == k*64+l
    float g1 = pg1[idx];
    float g2 = pg1[4096 + idx];
    float g3 = pg1[8192 + idx];
    WgA[idx] = g1 + g3;
    WgB[idx] = g2 - g3;
    float v1 = pv1[idx];
    float v2 = pv1[4096 + idx];
    float v3 = pv1[8192 + idx];
    WvA[idx] = v1 + v3;
    WvB[idx] = v2 - v3;
  } else {
    const int sub = threadIdx.x >> 6;
    const int lane = threadIdx.x & 63;
    const int b = (blk - 16) * 4 + sub;  // 0..15 = mat*8 + ks*4 + Mt
    const float* W = (b & 8) ? pv1 : pg1;
    const int Mt = b & 3;
    const int ks = (b >> 2) & 1;
    const int l = Mt * 16 + (lane & 15);
    const int kb = 192 + ks * 32 + (lane >> 4) * 8;  // |diff| block = rows 192..255
    uint4 o;
    o.x = bfpack(W[(kb + 0) * H + l], W[(kb + 1) * H + l]);
    o.y = bfpack(W[(kb + 2) * H + l], W[(kb + 3) * H + l]);
    o.z = bfpack(W[(kb + 4) * H + l], W[(kb + 5) * H + l]);
    o.w = bfpack(W[(kb + 6) * H + l], W[(kb + 7) * H + l]);
    ((uint4*)WF)[b * 64 + lane] = o;
  }
}

// ---------------- per-row projections: Ag/Av (bias folded) + interleaved transposed Bg/Bv
__global__ void k_ab(const float* __restrict__ enc, const float* __restrict__ WgA,
                     const float* __restrict__ WgB, const float* __restrict__ WvA,
                     const float* __restrict__ WvB, const float* __restrict__ pg_b1,
                     const float* __restrict__ pv_b1, float* __restrict__ Ag,
                     float* __restrict__ Av, float2* __restrict__ P4) {
  const int row = blockIdx.x;
  const int lane = threadIdx.x;
  __shared__ float erow[H];
  erow[lane] = enc[row * H + lane];
  __syncthreads();
  float ag = pg_b1[lane], bg = 0.f, av = pv_b1[lane], bv = 0.f;
#pragma unroll 4
  for (int k = 0; k < H; ++k) {
    float e = erow[k];
    ag += e * WgA[k * H + lane];
    bg += e * WgB[k * H + lane];
    av += e * WvA[k * H + lane];
    bv += e * WvB[k * H + lane];
  }
  Ag[row * H + lane] = ag;
  Av[row * H + lane] = av;
  int idx = (((row >> 4) * 4 + (lane >> 4)) * 4 + ((lane >> 2) & 3)) * 64 +
            (row & 15) * 4 + (lane & 3);
  P4[idx] = make_float2(bg, bv);
}

// ---------------- THE PAIR KERNEL (MFMA): one block per i, 4 waves split the j range.
// exp2-domain gates (log2e folded into pg_w2/pg_b2); defer-rescale via wave-uniform __any.
__global__ __launch_bounds__(256, 4) void k_pair(
    const float* __restrict__ enc, const float* __restrict__ Ag,
    const float* __restrict__ Av, const unsigned int* __restrict__ WF,
    const float2* __restrict__ P4, const float* __restrict__ pg_w2,
    const float* __restrict__ pg_b2, const float* __restrict__ pv_w2,
    const float* __restrict__ pv_b2, const float* __restrict__ lng,
    const float* __restrict__ lnb, float* __restrict__ enc2) {
  const int i = blockIdx.x;
  const int tid = threadIdx.x;
  const int lane = tid & 63;
  const int w = tid >> 6;  // 0..3: j-quarter
  const int l15 = lane & 15, g4 = lane >> 4;
  const float LOG2E = 1.44269504088896f;

  bf16x8 wg[2][4], wv[2][4];
  const uint4* WF4 = (const uint4*)WF;
#pragma unroll
  for (int ks = 0; ks < 2; ++ks)
#pragma unroll
    for (int Mt = 0; Mt < 4; ++Mt) {
      wg[ks][Mt] = __builtin_bit_cast(bf16x8, WF4[(ks * 4 + Mt) * 64 + lane]);
      wv[ks][Mt] = __builtin_bit_cast(bf16x8, WF4[((2 + ks) * 4 + Mt) * 64 + lane]);
    }

  const float* encI = enc + i * H;
  const float4 ei0 = *(const float4*)(encI + g4 * 8);
  const float4 ei1 = *(const float4*)(encI + g4 * 8 + 4);
  const float4 ei2 = *(const float4*)(encI + 32 + g4 * 8);
  const float4 ei3 = *(const float4*)(encI + 32 + g4 * 8 + 4);

  f32x4 agv[4], avv[4];
  float4 w2s[4];
#pragma unroll
  for (int Mt = 0; Mt < 4; ++Mt) {
    float4 t = *(const float4*)(Ag + i * H + Mt * 16 + g4 * 4);
    agv[Mt] = f32x4{t.x, t.y, t.z, t.w};
    float4 u = *(const float4*)(Av + i * H + Mt * 16 + g4 * 4);
    avv[Mt] = f32x4{u.x, u.y, u.z, u.w};
    float4 ww = *(const float4*)(pg_w2 + Mt * 16 + g4 * 4);
    w2s[Mt] = make_float4(ww.x * LOG2E, ww.y * LOG2E, ww.z * LOG2E, ww.w * LOG2E);
  }
  const float b2g = pg_b2[0] * LOG2E;

  float m = -3.0e38f, s = 0.f;
  float ctx[16];
#pragma unroll
  for (int e = 0; e < 16; ++e) ctx[e] = 0.f;

  const int jbase = w * 256;
  const float* ejp = enc + (jbase + l15) * H + g4 * 8;
  float4 na = *(const float4*)(ejp);
  float4 nb = *(const float4*)(ejp + 4);
  float4 nc = *(const float4*)(ejp + 32);
  float4 nd = *(const float4*)(ejp + 36);

#pragma unroll 1
  for (int t = 0; t < 16; ++t) {
    const int j0 = jbase + t * 16;
    float4 pq[8];
#pragma unroll
    for (int Mt = 0; Mt < 4; ++Mt) {
      const float4* pp =
          (const float4*)(P4 + (size_t)((((j0 >> 4) * 4 + Mt) * 4 + g4)) * 64 + l15 * 4);
      pq[Mt * 2 + 0] = pp[0];
      pq[Mt * 2 + 1] = pp[1];
    }
    bf16x8 b0, b1;
    b0[0] = bfc(fabsf(ei0.x - na.x)); b0[1] = bfc(fabsf(ei0.y - na.y));
    b0[2] = bfc(fabsf(ei0.z - na.z)); b0[3] = bfc(fabsf(ei0.w - na.w));
    b0[4] = bfc(fabsf(ei1.x - nb.x)); b0[5] = bfc(fabsf(ei1.y - nb.y));
    b0[6] = bfc(fabsf(ei1.z - nb.z)); b0[7] = bfc(fabsf(ei1.w - nb.w));
    b1[0] = bfc(fabsf(ei2.x - nc.x)); b1[1] = bfc(fabsf(ei2.y - nc.y));
    b1[2] = bfc(fabsf(ei2.z - nc.z)); b1[3] = bfc(fabsf(ei2.w - nc.w));
    b1[4] = bfc(fabsf(ei3.x - nd.x)); b1[5] = bfc(fabsf(ei3.y - nd.y));
    b1[6] = bfc(fabsf(ei3.z - nd.z)); b1[7] = bfc(fabsf(ei3.w - nd.w));
    ejp += 16 * H;  // last-iter read lands in enc2 region of d_ws: harmless, unused
    na = *(const float4*)(ejp);
    nb = *(const float4*)(ejp + 4);
    nc = *(const float4*)(ejp + 32);
    nd = *(const float4*)(ejp + 36);

    f32x4 cg[4], cv[4];
#pragma unroll
    for (int Mt = 0; Mt < 4; ++Mt) {
      cg[Mt] = __builtin_amdgcn_mfma_f32_16x16x32_bf16(wg[0][Mt], b0, agv[Mt], 0, 0, 0);
      cg[Mt] = __builtin_amdgcn_mfma_f32_16x16x32_bf16(wg[1][Mt], b1, cg[Mt], 0, 0, 0);
      cv[Mt] = __builtin_amdgcn_mfma_f32_16x16x32_bf16(wv[0][Mt], b0, avv[Mt], 0, 0, 0);
      cv[Mt] = __builtin_amdgcn_mfma_f32_16x16x32_bf16(wv[1][Mt], b1, cv[Mt], 0, 0, 0);
    }

    // gate (log2 domain) = sum_l relu(tg[l,j]) * w2log2e[l] + b2log2e
    float gate = 0.f;
#pragma unroll
    for (int Mt = 0; Mt < 4; ++Mt) {
      gate = fmaf(fmaxf(cg[Mt][0] + pq[Mt * 2].x, 0.f), w2s[Mt].x, gate);
      gate = fmaf(fmaxf(cg[Mt][1] + pq[Mt * 2].z, 0.f), w2s[Mt].y, gate);
      gate = fmaf(fmaxf(cg[Mt][2] + pq[Mt * 2 + 1].x, 0.f), w2s[Mt].z, gate);
      gate = fmaf(fmaxf(cg[Mt][3] + pq[Mt * 2 + 1].z, 0.f), w2s[Mt].w, gate);
    }
    gate += __shfl_xor(gate, 16, 64);
    gate += __shfl_xor(gate, 32, 64);
    gate += b2g;
    if (j0 + l15 == i) gate = -3.0e38f;  // diagonal mask (finite: avoids inf-inf)

    float val[16];
#pragma unroll
    for (int Mt = 0; Mt < 4; ++Mt) {
      val[Mt * 4 + 0] = fmaxf(cv[Mt][0] + pq[Mt * 2].y, 0.f);
      val[Mt * 4 + 1] = fmaxf(cv[Mt][1] + pq[Mt * 2].w, 0.f);
      val[Mt * 4 + 2] = fmaxf(cv[Mt][2] + pq[Mt * 2 + 1].y, 0.f);
      val[Mt * 4 + 3] = fmaxf(cv[Mt][3] + pq[Mt * 2 + 1].w, 0.f);
    }

    float p;
    if (__any(gate > m + 8.f)) {  // wave-uniform: rescale only when some lane's max grew
      float mn = fmaxf(m, gate);
      float c = exp2f(m - mn);
      p = exp2f(gate - mn);
      s = s * c;
      m = mn;
#pragma unroll
      for (int e = 0; e < 16; ++e) ctx[e] *= c;
    } else {
      p = exp2f(gate - m);  // bounded by 2^8
    }
    s += p;
#pragma unroll
    for (int e = 0; e < 16; ++e) ctx[e] = fmaf(p, val[e], ctx[e]);
  }

  // in-wave flash-merge across the 16 j-columns (xor butterfly over lane&15)
#pragma unroll
  for (int off = 1; off <= 8; off <<= 1) {
    float mo = __shfl_xor(m, off, 64);
    float so = __shfl_xor(s, off, 64);
    float M2 = fmaxf(m, mo);
    float ca = exp2f(m - M2);
    float cb = exp2f(mo - M2);
    s = s * ca + so * cb;
#pragma unroll
    for (int e = 0; e < 16; ++e) {
      float co = __shfl_xor(ctx[e], off, 64);
      ctx[e] = ctx[e] * ca + co * cb;
    }
    m = M2;
  }

  __shared__ float ctxs[4][64];
  __shared__ float mss[4][2];
  if (l15 == 0) {
#pragma unroll
    for (int Mt = 0; Mt < 4; ++Mt)
#pragma unroll
      for (int r = 0; r < 4; ++r) ctxs[w][Mt * 16 + g4 * 4 + r] = ctx[Mt * 4 + r];
  }
  if (lane == 0) {
    mss[w][0] = m;
    mss[w][1] = s;
  }
  __syncthreads();

  if (w == 0) {
    float M = fmaxf(fmaxf(mss[0][0], mss[1][0]), fmaxf(mss[2][0], mss[3][0]));
    float e0 = exp2f(mss[0][0] - M), e1 = exp2f(mss[1][0] - M);
    float e2 = exp2f(mss[2][0] - M), e3 = exp2f(mss[3][0] - M);
    float S = mss[0][1] * e0 + mss[1][1] * e1 + mss[2][1] * e2 + mss[3][1] * e3;
    float cp = (ctxs[0][lane] * e0 + ctxs[1][lane] * e1 + ctxs[2][lane] * e2 +
                ctxs[3][lane] * e3) / S;
    float pc = pv_b2[lane];
#pragma unroll 8
    for (int k = 0; k < 64; ++k) pc += __shfl(cp, k, 64) * pv_w2[k * H + lane];
    float x = enc[i * H + lane] + pc;
    float mu = wave_reduce_sum(x) * (1.f / 64.f);
    float dd = x - mu;
    float var = wave_reduce_sum(dd * dd) * (1.f / 64.f);
    enc2[i * H + lane] = dd * rsqrtf(var + 1e-5f) * lng[lane] + lnb[lane];
  }
}

// ---------------- column-sum stage 1: 32 blocks x 32 rows each
__global__ __launch_bounds__(256) void k_colsum(const float* __restrict__ enc2,
                                                float* __restrict__ part) {
  const int b = blockIdx.x;
  const int lane = threadIdx.x & 63, grp = threadIdx.x >> 6;
  const float* p = enc2 + (b * 32 + grp) * H + lane;
  float s = 0.f;
#pragma unroll
  for (int r = 0; r < 8; ++r) s += p[r * 4 * H];
  __shared__ float sh[4][64];
  sh[grp][lane] = s;
  __syncthreads();
  if (grp == 0) part[b * 64 + lane] = sh[0][lane] + sh[1][lane] + sh[2][lane] + sh[3][lane];
}

// ---------------- score head (graph-mean base folded in per-block)
__global__ void k_score(const float* __restrict__ enc2, const float* __restrict__ sh_w1,
                        const float* __restrict__ sh_b1, const float* __restrict__ sh_w2,
                        const float* __restrict__ sh_b2, const float* __restrict__ part,
                        float* __restrict__ out) {
  const int row = blockIdx.x;
  const int lane = threadIdx.x;
  __shared__ float erow[H];
  erow[lane] = enc2[row * H + lane];
  __syncthreads();
  float g = 0.f;
#pragma unroll
  for (int p = 0; p < 32; ++p) g += part[p * 64 + lane];
  g *= (1.f / N);
  float t = sh_b1[lane];
#pragma unroll 8
  for (int k = 0; k < 64; ++k) {
    t += erow[k] * sh_w1[k * H + lane];
    t += __shfl(g, k, 64) * sh_w1[(64 + k) * H + lane];
  }
  t = fmaxf(t, 0.f);
  float prt = t * sh_w2[lane];
  float sum = wave_reduce_sum(prt);
  if (lane == 0) out[row] = sum + sh_b2[0];
}

extern "C" void kernel_launch(void* const* d_in, const int* in_sizes, int n_in,
                              void* d_out, int out_size, void* d_ws, size_t ws_size,
                              hipStream_t stream) {
  const float* feat = (const float*)d_in[0];
  const float* ip_w1 = (const float*)d_in[1];
  const float* ip_b1 = (const float*)d_in[2];
  const float* ip_ln_g = (const float*)d_in[3];
  const float* ip_ln_b = (const float*)d_in[4];
  const float* ip_w2 = (const float*)d_in[5];
  const float* ip_b2 = (const float*)d_in[6];
  const float* attn_in_w = (const float*)d_in[7];
  const float* attn_in_b = (const float*)d_in[8];
  const float* attn_out_w = (const float*)d_in[9];
  const float* attn_out_b = (const float*)d_in[10];
  const float* attn_ln_g = (const float*)d_in[11];
  const float* attn_ln_b = (const float*)d_in[12];
  const float* pg_w1 = (const float*)d_in[13];
  const float* pg_b1 = (const float*)d_in[14];
  const float* pg_w2 = (const float*)d_in[15];
  const float* pg_b2 = (const float*)d_in[16];
  const float* pv_w1 = (const float*)d_in[17];
  const float* pv_b1 = (const float*)d_in[18];
  const float* pv_w2 = (const float*)d_in[19];
  const float* pv_b2 = (const float*)d_in[20];
  const float* ctx_ln_g = (const float*)d_in[21];
  const float* ctx_ln_b = (const float*)d_in[22];
  const float* sh_w1 = (const float*)d_in[23];
  const float* sh_b1 = (const float*)d_in[24];
  const float* sh_w2 = (const float*)d_in[25];
  const float* sh_b2 = (const float*)d_in[26];

  float* ws = (float*)d_ws;
  float* h = ws;                        // 0      .. 65536
  float* Qh = ws + 65536;               // 65536  .. 131072
  float* Kh = ws + 131072;              // 131072 .. 196608
  float* Vh = ws + 196608;              // 196608 .. 262144
  float* o = ws + 262144;               // 262144 .. 327680
  float* enc = ws + 327680;             // 327680 .. 393216
  float* enc2 = ws + 393216;            // 393216 .. 458752
  float2* P4 = (float2*)(ws + 65536);   // reuse Qh+Kh (128K floats)
  float* Ag = ws + 196608;              // reuse Vh
  float* Av = ws + 262144;              // reuse o
  float* WgA = ws + 458752;             // 4096 each
  float* WgB = ws + 462848;
  float* WvA = ws + 466944;
  float* WvB = ws + 471040;
  unsigned int* WF = (unsigned int*)(ws + 475136);  // 4096 u32
  float* part = ws + 479232;            // 2048
  float* out = (float*)d_out;

  k_input_qkv<<<N, 64, 0, stream>>>(feat, ip_w1, ip_b1, ip_ln_g, ip_ln_b, ip_w2, ip_b2,
                                    attn_in_w, attn_in_b, h, Qh, Kh, Vh);
  k_attn2<<<512, 256, 0, stream>>>(Qh, Kh, Vh, o);
  k_attn_out<<<N, 64, 0, stream>>>(o, attn_out_w, attn_out_b, h, attn_ln_g, attn_ln_b, enc);
  k_prep<<<20, 256, 0, stream>>>(pg_w1, pv_w1, WgA, WgB, WvA, WvB, WF);
  k_ab<<<N, 64, 0, stream>>>(enc, WgA, WgB, WvA, WvB, pg_b1, pv_b1, Ag, Av, P4);
  k_pair<<<N, 256, 0, stream>>>(enc, Ag, Av, WF, P4, pg_w2, pg_b2, pv_w2, pv_b2,
                                ctx_ln_g, ctx_ln_b, enc2);
  k_colsum<<<32, 256, 0, stream>>>(enc2, part);
  k_score<<<N, 64, 0, stream>>>(enc2, sh_w1, sh_b1, sh_w2, sh_b2, part, out);
}

// Round 6
// 170.318 us; speedup vs baseline: 2.1691x; 2.1691x over previous
//
#include <hip/hip_runtime.h>
#include <hip/hip_bf16.h>
#include <math.h>

#define N 1024
#define F 256
#define H 64

typedef __attribute__((ext_vector_type(8))) short bf16x8;
typedef __attribute__((ext_vector_type(4))) float f32x4;

__device__ __forceinline__ float wave_reduce_sum(float v) {
#pragma unroll
  for (int off = 32; off; off >>= 1) v += __shfl_xor(v, off, 64);
  return v;
}

__device__ __forceinline__ short bfc(float x) {
  __hip_bfloat16 h = __float2bfloat16(x);
  return __builtin_bit_cast(short, h);
}

__device__ __forceinline__ unsigned int bfpack(float a, float b) {
  return (unsigned int)(unsigned short)bfc(a) | ((unsigned int)(unsigned short)bfc(b) << 16);
}

// ---------------- FUSED input_proj + qkv: Linear->LN->ReLU->Linear->ReLU->qkv proj
__global__ void k_input_qkv(const float* __restrict__ feat,
                            const float* __restrict__ w1, const float* __restrict__ b1,
                            const float* __restrict__ lng, const float* __restrict__ lnb,
                            const float* __restrict__ w2, const float* __restrict__ b2,
                            const float* __restrict__ aw, const float* __restrict__ abias,
                            float* __restrict__ h, float* __restrict__ Qh,
                            float* __restrict__ Kh, float* __restrict__ Vh) {
  const int row = blockIdx.x;
  const int lane = threadIdx.x;  // 0..63
  __shared__ float frow[F];
#pragma unroll
  for (int c = 0; c < 4; ++c) frow[c * 64 + lane] = feat[row * F + c * 64 + lane];
  __syncthreads();
  float acc = b1[lane];
#pragma unroll 8
  for (int k = 0; k < F; ++k) acc += frow[k] * w1[k * H + lane];
  float mu = wave_reduce_sum(acc) * (1.f / 64.f);
  float d = acc - mu;
  float var = wave_reduce_sum(d * d) * (1.f / 64.f);
  float y = d * rsqrtf(var + 1e-5f) * lng[lane] + lnb[lane];
  y = fmaxf(y, 0.f);
  __shared__ float yrow[H];
  yrow[lane] = y;
  __syncthreads();
  float acc2 = b2[lane];
#pragma unroll 8
  for (int k = 0; k < H; ++k) acc2 += yrow[k] * w2[k * H + lane];
  float hv = fmaxf(acc2, 0.f);
  h[row * H + lane] = hv;
  __shared__ float hrow[H];
  hrow[lane] = hv;
  __syncthreads();
  float a0 = abias[lane], a1 = abias[64 + lane], a2 = abias[128 + lane];
#pragma unroll 8
  for (int k = 0; k < H; ++k) {
    float hk = hrow[k];
    a0 += hk * aw[k * 192 + lane];
    a1 += hk * aw[k * 192 + 64 + lane];
    a2 += hk * aw[k * 192 + 128 + lane];
  }
  const int base = (lane >> 4) * (N * 16) + row * 16 + (lane & 15);
  Qh[base] = a0;
  Kh[base] = a1;
  Vh[base] = a2;
}

// ---------------- attention v2: thread = (q-row, j-slot), private online softmax.
__global__ __launch_bounds__(256) void k_attn2(const float* __restrict__ Qh,
                                               const float* __restrict__ Kh,
                                               const float* __restrict__ Vh,
                                               float* __restrict__ o) {
  const int head = blockIdx.x >> 7;
  const int i0 = (blockIdx.x & 127) * 8;
  const int tid = threadIdx.x;
  const int q8 = tid >> 5, js = tid & 31;
  const int i = i0 + q8;

  const float* qp = Qh + head * (N * 16) + i * 16;
  const float4 q0 = *(const float4*)(qp);
  const float4 q1 = *(const float4*)(qp + 4);
  const float4 q2 = *(const float4*)(qp + 8);
  const float4 q3 = *(const float4*)(qp + 12);
  const float* kb = Kh + head * (N * 16);
  const float* vb = Vh + head * (N * 16);

  float m = -3.0e38f, s = 0.f;
  float4 c0 = {0, 0, 0, 0}, c1 = {0, 0, 0, 0}, c2 = {0, 0, 0, 0}, c3 = {0, 0, 0, 0};

  int j = js;
  const float* kp = kb + j * 16;
  const float* vp = vb + j * 16;
  float4 k0 = *(const float4*)(kp), k1 = *(const float4*)(kp + 4);
  float4 k2 = *(const float4*)(kp + 8), k3 = *(const float4*)(kp + 12);
  float4 v0 = *(const float4*)(vp), v1 = *(const float4*)(vp + 4);
  float4 v2 = *(const float4*)(vp + 8), v3 = *(const float4*)(vp + 12);

#pragma unroll 1
  for (int t = 0; t < 32; ++t) {
    const int jn = (j + 32) & (N - 1);  // last-iter wrap: in-bounds, result unused
    const float* kpn = kb + jn * 16;
    const float* vpn = vb + jn * 16;
    float4 nk0 = *(const float4*)(kpn), nk1 = *(const float4*)(kpn + 4);
    float4 nk2 = *(const float4*)(kpn + 8), nk3 = *(const float4*)(kpn + 12);
    float4 nv0 = *(const float4*)(vpn), nv1 = *(const float4*)(vpn + 4);
    float4 nv2 = *(const float4*)(vpn + 8), nv3 = *(const float4*)(vpn + 12);

    float sc = q0.x * k0.x + q0.y * k0.y + q0.z * k0.z + q0.w * k0.w;
    sc += q1.x * k1.x + q1.y * k1.y + q1.z * k1.z + q1.w * k1.w;
    sc += q2.x * k2.x + q2.y * k2.y + q2.z * k2.z + q2.w * k2.w;
    sc += q3.x * k3.x + q3.y * k3.y + q3.z * k3.z + q3.w * k3.w;
    sc *= 0.25f;  // 1/sqrt(16)

    float mn = fmaxf(m, sc);
    float cc = __expf(m - mn);
    float p = __expf(sc - mn);
    s = s * cc + p;
    m = mn;
    c0.x = c0.x * cc + p * v0.x; c0.y = c0.y * cc + p * v0.y;
    c0.z = c0.z * cc + p * v0.z; c0.w = c0.w * cc + p * v0.w;
    c1.x = c1.x * cc + p * v1.x; c1.y = c1.y * cc + p * v1.y;
    c1.z = c1.z * cc + p * v1.z; c1.w = c1.w * cc + p * v1.w;
    c2.x = c2.x * cc + p * v2.x; c2.y = c2.y * cc + p * v2.y;
    c2.z = c2.z * cc + p * v2.z; c2.w = c2.w * cc + p * v2.w;
    c3.x = c3.x * cc + p * v3.x; c3.y = c3.y * cc + p * v3.y;
    c3.z = c3.z * cc + p * v3.z; c3.w = c3.w * cc + p * v3.w;

    k0 = nk0; k1 = nk1; k2 = nk2; k3 = nk3;
    v0 = nv0; v1 = nv1; v2 = nv2; v3 = nv3;
    j = jn;
  }

  float M = m, S = s;
#pragma unroll
  for (int off = 16; off; off >>= 1) {
    float Mo = __shfl_xor(M, off, 64);
    float So = __shfl_xor(S, off, 64);
    float Mn = fmaxf(M, Mo);
    S = S * __expf(M - Mn) + So * __expf(Mo - Mn);
    M = Mn;
  }
  const float wgt = __expf(m - M) / S;

  __shared__ float lds[8][32][17];
  float* lp = &lds[q8][js][0];
  lp[0] = c0.x * wgt;  lp[1] = c0.y * wgt;  lp[2] = c0.z * wgt;  lp[3] = c0.w * wgt;
  lp[4] = c1.x * wgt;  lp[5] = c1.y * wgt;  lp[6] = c1.z * wgt;  lp[7] = c1.w * wgt;
  lp[8] = c2.x * wgt;  lp[9] = c2.y * wgt;  lp[10] = c2.z * wgt; lp[11] = c2.w * wgt;
  lp[12] = c3.x * wgt; lp[13] = c3.y * wgt; lp[14] = c3.z * wgt; lp[15] = c3.w * wgt;
  __syncthreads();

  if (tid < 128) {
    const int q = tid >> 4, d = tid & 15;
    float sum = 0.f;
#pragma unroll
    for (int k = 0; k < 32; ++k) sum += lds[q][k][d];
    o[(i0 + q) * H + head * 16 + d] = sum;
  }
}

// ---------------- attn out proj + residual + LN -> enc
__global__ void k_attn_out(const float* __restrict__ o, const float* __restrict__ w,
                           const float* __restrict__ b, const float* __restrict__ h,
                           const float* __restrict__ lng, const float* __restrict__ lnb,
                           float* __restrict__ enc) {
  const int row = blockIdx.x;
  const int lane = threadIdx.x;
  __shared__ float orow[H];
  orow[lane] = o[row * H + lane];
  __syncthreads();
  float a = b[lane];
#pragma unroll 8
  for (int k = 0; k < H; ++k) a += orow[k] * w[k * H + lane];
  float x = h[row * H + lane] + a;
  float mu = wave_reduce_sum(x) * (1.f / 64.f);
  float d = x - mu;
  float var = wave_reduce_sum(d * d) * (1.f / 64.f);
  enc[row * H + lane] = d * rsqrtf(var + 1e-5f) * lng[lane] + lnb[lane];
}

// ---------------- MERGED prep: blocks 0..15 = combos; blocks 16..19 = W4^T MFMA frags
__global__ __launch_bounds__(256) void k_prep(const float* __restrict__ pg1,
                                              const float* __restrict__ pv1,
                                              float* __restrict__ WgA, float* __restrict__ WgB,
                                              float* __restrict__ WvA, float* __restrict__ WvB,
                                              unsigned int* __restrict__ WF) {
  const int blk = blockIdx.x;
  if (blk < 16) {
    int idx = blk * 256 + threadIdx.x;  // 0..4095 == k*64+l
    float g1 = pg1[idx];
    float g2 = pg1[4096 + idx];
    float g3 = pg1[8192 + idx];
    WgA[idx] = g1 + g3;
    WgB[idx] = g2 - g3;
    float v1 = pv1[idx];
    float v2 = pv1[4096 + idx];
    float v3 = pv1[8192 + idx];
    WvA[idx] = v1 + v3;
    WvB[idx] = v2 - v3;
  } else {
    const int sub = threadIdx.x >> 6;
    const int lane = threadIdx.x & 63;
    const int b = (blk - 16) * 4 + sub;  // 0..15 = mat*8 + ks*4 + Mt
    const float* W = (b & 8) ? pv1 : pg1;
    const int Mt = b & 3;
    const int ks = (b >> 2) & 1;
    const int l = Mt * 16 + (lane & 15);
    const int kb = 192 + ks * 32 + (lane >> 4) * 8;  // |diff| block = rows 192..255
    uint4 o;
    o.x = bfpack(W[(kb + 0) * H + l], W[(kb + 1) * H + l]);
    o.y = bfpack(W[(kb + 2) * H + l], W[(kb + 3) * H + l]);
    o.z = bfpack(W[(kb + 4) * H + l], W[(kb + 5) * H + l]);
    o.w = bfpack(W[(kb + 6) * H + l], W[(kb + 7) * H + l]);
    ((uint4*)WF)[b * 64 + lane] = o;
  }
}

// ---------------- per-row projections: Ag/Av (bias folded) + interleaved transposed Bg/Bv
__global__ void k_ab(const float* __restrict__ enc, const float* __restrict__ WgA,
                     const float* __restrict__ WgB, const float* __restrict__ WvA,
                     const float* __restrict__ WvB, const float* __restrict__ pg_b1,
                     const float* __restrict__ pv_b1, float* __restrict__ Ag,
                     float* __restrict__ Av, float2* __restrict__ P4) {
  const int row = blockIdx.x;
  const int lane = threadIdx.x;
  __shared__ float erow[H];
  erow[lane] = enc[row * H + lane];
  __syncthreads();
  float ag = pg_b1[lane], bg = 0.f, av = pv_b1[lane], bv = 0.f;
#pragma unroll 4
  for (int k = 0; k < H; ++k) {
    float e = erow[k];
    ag += e * WgA[k * H + lane];
    bg += e * WgB[k * H + lane];
    av += e * WvA[k * H + lane];
    bv += e * WvB[k * H + lane];
  }
  Ag[row * H + lane] = ag;
  Av[row * H + lane] = av;
  int idx = (((row >> 4) * 4 + (lane >> 4)) * 4 + ((lane >> 2) & 3)) * 64 +
            (row & 15) * 4 + (lane & 3);
  P4[idx] = make_float2(bg, bv);
}

// ---------------- THE PAIR KERNEL (MFMA): one block per i, 4 waves split the j range.
// launch_bounds (256,2): combined VGPR+AGPR cap 256 -> NO SPILL (R5's (256,4) forced
// a 128-reg cap on the unified file and spilled ~1GB/dispatch).
// P4 loads double-buffered one tile ahead; exp2-domain gates; defer-rescale.
__global__ __launch_bounds__(256, 2) void k_pair(
    const float* __restrict__ enc, const float* __restrict__ Ag,
    const float* __restrict__ Av, const unsigned int* __restrict__ WF,
    const float2* __restrict__ P4, const float* __restrict__ pg_w2,
    const float* __restrict__ pg_b2, const float* __restrict__ pv_w2,
    const float* __restrict__ pv_b2, const float* __restrict__ lng,
    const float* __restrict__ lnb, float* __restrict__ enc2) {
  const int i = blockIdx.x;
  const int tid = threadIdx.x;
  const int lane = tid & 63;
  const int w = tid >> 6;  // 0..3: j-quarter
  const int l15 = lane & 15, g4 = lane >> 4;
  const float LOG2E = 1.44269504088896f;

  bf16x8 wg[2][4], wv[2][4];
  const uint4* WF4 = (const uint4*)WF;
#pragma unroll
  for (int ks = 0; ks < 2; ++ks)
#pragma unroll
    for (int Mt = 0; Mt < 4; ++Mt) {
      wg[ks][Mt] = __builtin_bit_cast(bf16x8, WF4[(ks * 4 + Mt) * 64 + lane]);
      wv[ks][Mt] = __builtin_bit_cast(bf16x8, WF4[((2 + ks) * 4 + Mt) * 64 + lane]);
    }

  const float* encI = enc + i * H;
  const float4 ei0 = *(const float4*)(encI + g4 * 8);
  const float4 ei1 = *(const float4*)(encI + g4 * 8 + 4);
  const float4 ei2 = *(const float4*)(encI + 32 + g4 * 8);
  const float4 ei3 = *(const float4*)(encI + 32 + g4 * 8 + 4);

  f32x4 agv[4], avv[4];
  float4 w2s[4];
#pragma unroll
  for (int Mt = 0; Mt < 4; ++Mt) {
    float4 t = *(const float4*)(Ag + i * H + Mt * 16 + g4 * 4);
    agv[Mt] = f32x4{t.x, t.y, t.z, t.w};
    float4 u = *(const float4*)(Av + i * H + Mt * 16 + g4 * 4);
    avv[Mt] = f32x4{u.x, u.y, u.z, u.w};
    float4 ww = *(const float4*)(pg_w2 + Mt * 16 + g4 * 4);
    w2s[Mt] = make_float4(ww.x * LOG2E, ww.y * LOG2E, ww.z * LOG2E, ww.w * LOG2E);
  }
  const float b2g = pg_b2[0] * LOG2E;

  float m = -3.0e38f, s = 0.f;
  float ctx[16];
#pragma unroll
  for (int e = 0; e < 16; ++e) ctx[e] = 0.f;

  const int jbase = w * 256;
  const float* ejp = enc + (jbase + l15) * H + g4 * 8;
  float4 na = *(const float4*)(ejp);
  float4 nb = *(const float4*)(ejp + 4);
  float4 nc = *(const float4*)(ejp + 32);
  float4 nd = *(const float4*)(ejp + 36);

  float4 pqA[8], pqB[8];

  auto loadpq = [&](float4* dst, int t) {
    const int j0 = jbase + t * 16;
#pragma unroll
    for (int Mt = 0; Mt < 4; ++Mt) {
      const float4* pp =
          (const float4*)(P4 + (size_t)((((j0 >> 4) * 4 + Mt) * 4 + g4)) * 64 + l15 * 4);
      dst[Mt * 2 + 0] = pp[0];
      dst[Mt * 2 + 1] = pp[1];
    }
  };

  auto tile = [&](int t, const float4* pq) {
    const int j0 = jbase + t * 16;
    // B fragments: |enc_i - enc_j|^T, lane = col j0+l15, k = ks*32 + g4*8 + e
    bf16x8 b0, b1;
    b0[0] = bfc(fabsf(ei0.x - na.x)); b0[1] = bfc(fabsf(ei0.y - na.y));
    b0[2] = bfc(fabsf(ei0.z - na.z)); b0[3] = bfc(fabsf(ei0.w - na.w));
    b0[4] = bfc(fabsf(ei1.x - nb.x)); b0[5] = bfc(fabsf(ei1.y - nb.y));
    b0[6] = bfc(fabsf(ei1.z - nb.z)); b0[7] = bfc(fabsf(ei1.w - nb.w));
    b1[0] = bfc(fabsf(ei2.x - nc.x)); b1[1] = bfc(fabsf(ei2.y - nc.y));
    b1[2] = bfc(fabsf(ei2.z - nc.z)); b1[3] = bfc(fabsf(ei2.w - nc.w));
    b1[4] = bfc(fabsf(ei3.x - nd.x)); b1[5] = bfc(fabsf(ei3.y - nd.y));
    b1[6] = bfc(fabsf(ei3.z - nd.z)); b1[7] = bfc(fabsf(ei3.w - nd.w));
    // prefetch next tile's ej (last-iter read lands in enc2 region of ws: unused)
    ejp += 16 * H;
    na = *(const float4*)(ejp);
    nb = *(const float4*)(ejp + 4);
    nc = *(const float4*)(ejp + 32);
    nd = *(const float4*)(ejp + 36);

    f32x4 cg[4], cv[4];
#pragma unroll
    for (int Mt = 0; Mt < 4; ++Mt) {
      cg[Mt] = __builtin_amdgcn_mfma_f32_16x16x32_bf16(wg[0][Mt], b0, agv[Mt], 0, 0, 0);
      cg[Mt] = __builtin_amdgcn_mfma_f32_16x16x32_bf16(wg[1][Mt], b1, cg[Mt], 0, 0, 0);
      cv[Mt] = __builtin_amdgcn_mfma_f32_16x16x32_bf16(wv[0][Mt], b0, avv[Mt], 0, 0, 0);
      cv[Mt] = __builtin_amdgcn_mfma_f32_16x16x32_bf16(wv[1][Mt], b1, cv[Mt], 0, 0, 0);
    }

    // gate (log2 domain) = sum_l relu(tg[l,j]) * w2log2e[l] + b2log2e
    float gate = 0.f;
#pragma unroll
    for (int Mt = 0; Mt < 4; ++Mt) {
      gate = fmaf(fmaxf(cg[Mt][0] + pq[Mt * 2].x, 0.f), w2s[Mt].x, gate);
      gate = fmaf(fmaxf(cg[Mt][1] + pq[Mt * 2].z, 0.f), w2s[Mt].y, gate);
      gate = fmaf(fmaxf(cg[Mt][2] + pq[Mt * 2 + 1].x, 0.f), w2s[Mt].z, gate);
      gate = fmaf(fmaxf(cg[Mt][3] + pq[Mt * 2 + 1].z, 0.f), w2s[Mt].w, gate);
    }
    gate += __shfl_xor(gate, 16, 64);
    gate += __shfl_xor(gate, 32, 64);
    gate += b2g;
    if (j0 + l15 == i) gate = -3.0e38f;  // diagonal mask

    float p;
    if (__any(gate > m + 8.f)) {  // wave-uniform: rescale only when some lane's max grew
      float mn = fmaxf(m, gate);
      float c = exp2f(m - mn);
      p = exp2f(gate - mn);
      s *= c;
      m = mn;
#pragma unroll
      for (int e = 0; e < 16; ++e) ctx[e] *= c;
    } else {
      p = exp2f(gate - m);  // bounded by 2^8
    }
    s += p;
#pragma unroll
    for (int Mt = 0; Mt < 4; ++Mt) {
      ctx[Mt * 4 + 0] = fmaf(p, fmaxf(cv[Mt][0] + pq[Mt * 2].y, 0.f), ctx[Mt * 4 + 0]);
      ctx[Mt * 4 + 1] = fmaf(p, fmaxf(cv[Mt][1] + pq[Mt * 2].w, 0.f), ctx[Mt * 4 + 1]);
      ctx[Mt * 4 + 2] = fmaf(p, fmaxf(cv[Mt][2] + pq[Mt * 2 + 1].y, 0.f), ctx[Mt * 4 + 2]);
      ctx[Mt * 4 + 3] = fmaf(p, fmaxf(cv[Mt][3] + pq[Mt * 2 + 1].w, 0.f), ctx[Mt * 4 + 3]);
    }
  };

  loadpq(pqA, 0);
#pragma unroll 1
  for (int tt = 0; tt < 8; ++tt) {
    loadpq(pqB, tt * 2 + 1);            // prefetch odd tile
    tile(tt * 2, pqA);                  // compute even tile
    loadpq(pqA, tt == 7 ? 15 : tt * 2 + 2);  // prefetch next even (clamped, in-bounds)
    tile(tt * 2 + 1, pqB);              // compute odd tile
  }

  // in-wave flash-merge across the 16 j-columns (xor butterfly over lane&15)
#pragma unroll
  for (int off = 1; off <= 8; off <<= 1) {
    float mo = __shfl_xor(m, off, 64);
    float so = __shfl_xor(s, off, 64);
    float M2 = fmaxf(m, mo);
    float ca = exp2f(m - M2);
    float cb = exp2f(mo - M2);
    s = s * ca + so * cb;
#pragma unroll
    for (int e = 0; e < 16; ++e) {
      float co = __shfl_xor(ctx[e], off, 64);
      ctx[e] = ctx[e] * ca + co * cb;
    }
    m = M2;
  }

  __shared__ float ctxs[4][64];
  __shared__ float mss[4][2];
  if (l15 == 0) {
#pragma unroll
    for (int Mt = 0; Mt < 4; ++Mt)
#pragma unroll
      for (int r = 0; r < 4; ++r) ctxs[w][Mt * 16 + g4 * 4 + r] = ctx[Mt * 4 + r];
  }
  if (lane == 0) {
    mss[w][0] = m;
    mss[w][1] = s;
  }
  __syncthreads();

  if (w == 0) {
    float M = fmaxf(fmaxf(mss[0][0], mss[1][0]), fmaxf(mss[2][0], mss[3][0]));
    float e0 = exp2f(mss[0][0] - M), e1 = exp2f(mss[1][0] - M);
    float e2 = exp2f(mss[2][0] - M), e3 = exp2f(mss[3][0] - M);
    float S = mss[0][1] * e0 + mss[1][1] * e1 + mss[2][1] * e2 + mss[3][1] * e3;
    float cp = (ctxs[0][lane] * e0 + ctxs[1][lane] * e1 + ctxs[2][lane] * e2 +
                ctxs[3][lane] * e3) / S;
    float pc = pv_b2[lane];
#pragma unroll 8
    for (int k = 0; k < 64; ++k) pc += __shfl(cp, k, 64) * pv_w2[k * H + lane];
    float x = enc[i * H + lane] + pc;
    float mu = wave_reduce_sum(x) * (1.f / 64.f);
    float dd = x - mu;
    float var = wave_reduce_sum(dd * dd) * (1.f / 64.f);
    enc2[i * H + lane] = dd * rsqrtf(var + 1e-5f) * lng[lane] + lnb[lane];
  }
}

// ---------------- column-sum stage 1: 32 blocks x 32 rows each
__global__ __launch_bounds__(256) void k_colsum(const float* __restrict__ enc2,
                                                float* __restrict__ part) {
  const int b = blockIdx.x;
  const int lane = threadIdx.x & 63, grp = threadIdx.x >> 6;
  const float* p = enc2 + (b * 32 + grp) * H + lane;
  float s = 0.f;
#pragma unroll
  for (int r = 0; r < 8; ++r) s += p[r * 4 * H];
  __shared__ float sh[4][64];
  sh[grp][lane] = s;
  __syncthreads();
  if (grp == 0) part[b * 64 + lane] = sh[0][lane] + sh[1][lane] + sh[2][lane] + sh[3][lane];
}

// ---------------- score head (graph-mean base folded in per-block)
__global__ void k_score(const float* __restrict__ enc2, const float* __restrict__ sh_w1,
                        const float* __restrict__ sh_b1, const float* __restrict__ sh_w2,
                        const float* __restrict__ sh_b2, const float* __restrict__ part,
                        float* __restrict__ out) {
  const int row = blockIdx.x;
  const int lane = threadIdx.x;
  __shared__ float erow[H];
  erow[lane] = enc2[row * H + lane];
  __syncthreads();
  float g = 0.f;
#pragma unroll
  for (int p = 0; p < 32; ++p) g += part[p * 64 + lane];
  g *= (1.f / N);
  float t = sh_b1[lane];
#pragma unroll 8
  for (int k = 0; k < 64; ++k) {
    t += erow[k] * sh_w1[k * H + lane];
    t += __shfl(g, k, 64) * sh_w1[(64 + k) * H + lane];
  }
  t = fmaxf(t, 0.f);
  float prt = t * sh_w2[lane];
  float sum = wave_reduce_sum(prt);
  if (lane == 0) out[row] = sum + sh_b2[0];
}

extern "C" void kernel_launch(void* const* d_in, const int* in_sizes, int n_in,
                              void* d_out, int out_size, void* d_ws, size_t ws_size,
                              hipStream_t stream) {
  const float* feat = (const float*)d_in[0];
  const float* ip_w1 = (const float*)d_in[1];
  const float* ip_b1 = (const float*)d_in[2];
  const float* ip_ln_g = (const float*)d_in[3];
  const float* ip_ln_b = (const float*)d_in[4];
  const float* ip_w2 = (const float*)d_in[5];
  const float* ip_b2 = (const float*)d_in[6];
  const float* attn_in_w = (const float*)d_in[7];
  const float* attn_in_b = (const float*)d_in[8];
  const float* attn_out_w = (const float*)d_in[9];
  const float* attn_out_b = (const float*)d_in[10];
  const float* attn_ln_g = (const float*)d_in[11];
  const float* attn_ln_b = (const float*)d_in[12];
  const float* pg_w1 = (const float*)d_in[13];
  const float* pg_b1 = (const float*)d_in[14];
  const float* pg_w2 = (const float*)d_in[15];
  const float* pg_b2 = (const float*)d_in[16];
  const float* pv_w1 = (const float*)d_in[17];
  const float* pv_b1 = (const float*)d_in[18];
  const float* pv_w2 = (const float*)d_in[19];
  const float* pv_b2 = (const float*)d_in[20];
  const float* ctx_ln_g = (const float*)d_in[21];
  const float* ctx_ln_b = (const float*)d_in[22];
  const float* sh_w1 = (const float*)d_in[23];
  const float* sh_b1 = (const float*)d_in[24];
  const float* sh_w2 = (const float*)d_in[25];
  const float* sh_b2 = (const float*)d_in[26];

  float* ws = (float*)d_ws;
  float* h = ws;                        // 0      .. 65536
  float* Qh = ws + 65536;               // 65536  .. 131072
  float* Kh = ws + 131072;              // 131072 .. 196608
  float* Vh = ws + 196608;              // 196608 .. 262144
  float* o = ws + 262144;               // 262144 .. 327680
  float* enc = ws + 327680;             // 327680 .. 393216
  float* enc2 = ws + 393216;            // 393216 .. 458752
  float2* P4 = (float2*)(ws + 65536);   // reuse Qh+Kh (128K floats)
  float* Ag = ws + 196608;              // reuse Vh
  float* Av = ws + 262144;              // reuse o
  float* WgA = ws + 458752;             // 4096 each
  float* WgB = ws + 462848;
  float* WvA = ws + 466944;
  float* WvB = ws + 471040;
  unsigned int* WF = (unsigned int*)(ws + 475136);  // 4096 u32
  float* part = ws + 479232;            // 2048
  float* out = (float*)d_out;

  k_input_qkv<<<N, 64, 0, stream>>>(feat, ip_w1, ip_b1, ip_ln_g, ip_ln_b, ip_w2, ip_b2,
                                    attn_in_w, attn_in_b, h, Qh, Kh, Vh);
  k_attn2<<<512, 256, 0, stream>>>(Qh, Kh, Vh, o);
  k_attn_out<<<N, 64, 0, stream>>>(o, attn_out_w, attn_out_b, h, attn_ln_g, attn_ln_b, enc);
  k_prep<<<20, 256, 0, stream>>>(pg_w1, pv_w1, WgA, WgB, WvA, WvB, WF);
  k_ab<<<N, 64, 0, stream>>>(enc, WgA, WgB, WvA, WvB, pg_b1, pv_b1, Ag, Av, P4);
  k_pair<<<N, 256, 0, stream>>>(enc, Ag, Av, WF, P4, pg_w2, pg_b2, pv_w2, pv_b2,
                                ctx_ln_g, ctx_ln_b, enc2);
  k_colsum<<<32, 256, 0, stream>>>(enc2, part);
  k_score<<<N, 64, 0, stream>>>(enc2, sh_w1, sh_b1, sh_w2, sh_b2, part, out);
}

// Round 7
// 129.853 us; speedup vs baseline: 2.8450x; 1.3116x over previous
//
#include <hip/hip_runtime.h>
#include <hip/hip_bf16.h>
#include <math.h>

#define N 1024
#define F 256
#define H 64

typedef __attribute__((ext_vector_type(8))) short bf16x8;
typedef __attribute__((ext_vector_type(4))) float f32x4;

__device__ __forceinline__ float wave_reduce_sum(float v) {
#pragma unroll
  for (int off = 32; off; off >>= 1) v += __shfl_xor(v, off, 64);
  return v;
}

__device__ __forceinline__ short bfc(float x) {
  __hip_bfloat16 h = __float2bfloat16(x);
  return __builtin_bit_cast(short, h);
}

__device__ __forceinline__ unsigned int bfpack(float a, float b) {
  return (unsigned int)(unsigned short)bfc(a) | ((unsigned int)(unsigned short)bfc(b) << 16);
}

// ---------------- FUSED input_proj + qkv: Linear->LN->ReLU->Linear->ReLU->qkv proj
__global__ void k_input_qkv(const float* __restrict__ feat,
                            const float* __restrict__ w1, const float* __restrict__ b1,
                            const float* __restrict__ lng, const float* __restrict__ lnb,
                            const float* __restrict__ w2, const float* __restrict__ b2,
                            const float* __restrict__ aw, const float* __restrict__ abias,
                            float* __restrict__ h, float* __restrict__ Qh,
                            float* __restrict__ Kh, float* __restrict__ Vh) {
  const int row = blockIdx.x;
  const int lane = threadIdx.x;  // 0..63
  __shared__ float frow[F];
#pragma unroll
  for (int c = 0; c < 4; ++c) frow[c * 64 + lane] = feat[row * F + c * 64 + lane];
  __syncthreads();
  float acc = b1[lane];
#pragma unroll 8
  for (int k = 0; k < F; ++k) acc += frow[k] * w1[k * H + lane];
  float mu = wave_reduce_sum(acc) * (1.f / 64.f);
  float d = acc - mu;
  float var = wave_reduce_sum(d * d) * (1.f / 64.f);
  float y = d * rsqrtf(var + 1e-5f) * lng[lane] + lnb[lane];
  y = fmaxf(y, 0.f);
  __shared__ float yrow[H];
  yrow[lane] = y;
  __syncthreads();
  float acc2 = b2[lane];
#pragma unroll 8
  for (int k = 0; k < H; ++k) acc2 += yrow[k] * w2[k * H + lane];
  float hv = fmaxf(acc2, 0.f);
  h[row * H + lane] = hv;
  __shared__ float hrow[H];
  hrow[lane] = hv;
  __syncthreads();
  float a0 = abias[lane], a1 = abias[64 + lane], a2 = abias[128 + lane];
#pragma unroll 8
  for (int k = 0; k < H; ++k) {
    float hk = hrow[k];
    a0 += hk * aw[k * 192 + lane];
    a1 += hk * aw[k * 192 + 64 + lane];
    a2 += hk * aw[k * 192 + 128 + lane];
  }
  const int base = (lane >> 4) * (N * 16) + row * 16 + (lane & 15);
  Qh[base] = a0;
  Kh[base] = a1;
  Vh[base] = a2;
}

// ---------------- attention v2: thread = (q-row, j-slot), private online softmax.
__global__ __launch_bounds__(256) void k_attn2(const float* __restrict__ Qh,
                                               const float* __restrict__ Kh,
                                               const float* __restrict__ Vh,
                                               float* __restrict__ o) {
  const int head = blockIdx.x >> 7;
  const int i0 = (blockIdx.x & 127) * 8;
  const int tid = threadIdx.x;
  const int q8 = tid >> 5, js = tid & 31;
  const int i = i0 + q8;

  const float* qp = Qh + head * (N * 16) + i * 16;
  const float4 q0 = *(const float4*)(qp);
  const float4 q1 = *(const float4*)(qp + 4);
  const float4 q2 = *(const float4*)(qp + 8);
  const float4 q3 = *(const float4*)(qp + 12);
  const float* kb = Kh + head * (N * 16);
  const float* vb = Vh + head * (N * 16);

  float m = -3.0e38f, s = 0.f;
  float4 c0 = {0, 0, 0, 0}, c1 = {0, 0, 0, 0}, c2 = {0, 0, 0, 0}, c3 = {0, 0, 0, 0};

  int j = js;
  const float* kp = kb + j * 16;
  const float* vp = vb + j * 16;
  float4 k0 = *(const float4*)(kp), k1 = *(const float4*)(kp + 4);
  float4 k2 = *(const float4*)(kp + 8), k3 = *(const float4*)(kp + 12);
  float4 v0 = *(const float4*)(vp), v1 = *(const float4*)(vp + 4);
  float4 v2 = *(const float4*)(vp + 8), v3 = *(const float4*)(vp + 12);

#pragma unroll 1
  for (int t = 0; t < 32; ++t) {
    const int jn = (j + 32) & (N - 1);  // last-iter wrap: in-bounds, result unused
    const float* kpn = kb + jn * 16;
    const float* vpn = vb + jn * 16;
    float4 nk0 = *(const float4*)(kpn), nk1 = *(const float4*)(kpn + 4);
    float4 nk2 = *(const float4*)(kpn + 8), nk3 = *(const float4*)(kpn + 12);
    float4 nv0 = *(const float4*)(vpn), nv1 = *(const float4*)(vpn + 4);
    float4 nv2 = *(const float4*)(vpn + 8), nv3 = *(const float4*)(vpn + 12);

    float sc = q0.x * k0.x + q0.y * k0.y + q0.z * k0.z + q0.w * k0.w;
    sc += q1.x * k1.x + q1.y * k1.y + q1.z * k1.z + q1.w * k1.w;
    sc += q2.x * k2.x + q2.y * k2.y + q2.z * k2.z + q2.w * k2.w;
    sc += q3.x * k3.x + q3.y * k3.y + q3.z * k3.z + q3.w * k3.w;
    sc *= 0.25f;  // 1/sqrt(16)

    float mn = fmaxf(m, sc);
    float cc = __expf(m - mn);
    float p = __expf(sc - mn);
    s = s * cc + p;
    m = mn;
    c0.x = c0.x * cc + p * v0.x; c0.y = c0.y * cc + p * v0.y;
    c0.z = c0.z * cc + p * v0.z; c0.w = c0.w * cc + p * v0.w;
    c1.x = c1.x * cc + p * v1.x; c1.y = c1.y * cc + p * v1.y;
    c1.z = c1.z * cc + p * v1.z; c1.w = c1.w * cc + p * v1.w;
    c2.x = c2.x * cc + p * v2.x; c2.y = c2.y * cc + p * v2.y;
    c2.z = c2.z * cc + p * v2.z; c2.w = c2.w * cc + p * v2.w;
    c3.x = c3.x * cc + p * v3.x; c3.y = c3.y * cc + p * v3.y;
    c3.z = c3.z * cc + p * v3.z; c3.w = c3.w * cc + p * v3.w;

    k0 = nk0; k1 = nk1; k2 = nk2; k3 = nk3;
    v0 = nv0; v1 = nv1; v2 = nv2; v3 = nv3;
    j = jn;
  }

  float M = m, S = s;
#pragma unroll
  for (int off = 16; off; off >>= 1) {
    float Mo = __shfl_xor(M, off, 64);
    float So = __shfl_xor(S, off, 64);
    float Mn = fmaxf(M, Mo);
    S = S * __expf(M - Mn) + So * __expf(Mo - Mn);
    M = Mn;
  }
  const float wgt = __expf(m - M) / S;

  __shared__ float lds[8][32][17];
  float* lp = &lds[q8][js][0];
  lp[0] = c0.x * wgt;  lp[1] = c0.y * wgt;  lp[2] = c0.z * wgt;  lp[3] = c0.w * wgt;
  lp[4] = c1.x * wgt;  lp[5] = c1.y * wgt;  lp[6] = c1.z * wgt;  lp[7] = c1.w * wgt;
  lp[8] = c2.x * wgt;  lp[9] = c2.y * wgt;  lp[10] = c2.z * wgt; lp[11] = c2.w * wgt;
  lp[12] = c3.x * wgt; lp[13] = c3.y * wgt; lp[14] = c3.z * wgt; lp[15] = c3.w * wgt;
  __syncthreads();

  if (tid < 128) {
    const int q = tid >> 4, d = tid & 15;
    float sum = 0.f;
#pragma unroll
    for (int k = 0; k < 32; ++k) sum += lds[q][k][d];
    o[(i0 + q) * H + head * 16 + d] = sum;
  }
}

// ---------------- attn out proj + residual + LN -> enc
__global__ void k_attn_out(const float* __restrict__ o, const float* __restrict__ w,
                           const float* __restrict__ b, const float* __restrict__ h,
                           const float* __restrict__ lng, const float* __restrict__ lnb,
                           float* __restrict__ enc) {
  const int row = blockIdx.x;
  const int lane = threadIdx.x;
  __shared__ float orow[H];
  orow[lane] = o[row * H + lane];
  __syncthreads();
  float a = b[lane];
#pragma unroll 8
  for (int k = 0; k < H; ++k) a += orow[k] * w[k * H + lane];
  float x = h[row * H + lane] + a;
  float mu = wave_reduce_sum(x) * (1.f / 64.f);
  float d = x - mu;
  float var = wave_reduce_sum(d * d) * (1.f / 64.f);
  enc[row * H + lane] = d * rsqrtf(var + 1e-5f) * lng[lane] + lnb[lane];
}

// ---------------- MERGED prep: blocks 0..15 = combos; blocks 16..19 = W4^T MFMA frags
__global__ __launch_bounds__(256) void k_prep(const float* __restrict__ pg1,
                                              const float* __restrict__ pv1,
                                              float* __restrict__ WgA, float* __restrict__ WgB,
                                              float* __restrict__ WvA, float* __restrict__ WvB,
                                              unsigned int* __restrict__ WF) {
  const int blk = blockIdx.x;
  if (blk < 16) {
    int idx = blk * 256 + threadIdx.x;  // 0..4095 == k*64+l
    float g1 = pg1[idx];
    float g2 = pg1[4096 + idx];
    float g3 = pg1[8192 + idx];
    WgA[idx] = g1 + g3;
    WgB[idx] = g2 - g3;
    float v1 = pv1[idx];
    float v2 = pv1[4096 + idx];
    float v3 = pv1[8192 + idx];
    WvA[idx] = v1 + v3;
    WvB[idx] = v2 - v3;
  } else {
    const int sub = threadIdx.x >> 6;
    const int lane = threadIdx.x & 63;
    const int b = (blk - 16) * 4 + sub;  // 0..15 = mat*8 + ks*4 + Mt
    const float* W = (b & 8) ? pv1 : pg1;
    const int Mt = b & 3;
    const int ks = (b >> 2) & 1;
    const int l = Mt * 16 + (lane & 15);
    const int kb = 192 + ks * 32 + (lane >> 4) * 8;  // |diff| block = rows 192..255
    uint4 o;
    o.x = bfpack(W[(kb + 0) * H + l], W[(kb + 1) * H + l]);
    o.y = bfpack(W[(kb + 2) * H + l], W[(kb + 3) * H + l]);
    o.z = bfpack(W[(kb + 4) * H + l], W[(kb + 5) * H + l]);
    o.w = bfpack(W[(kb + 6) * H + l], W[(kb + 7) * H + l]);
    ((uint4*)WF)[b * 64 + lane] = o;
  }
}

// ---------------- per-row projections: Ag/Av (bias folded) + interleaved transposed Bg/Bv
__global__ void k_ab(const float* __restrict__ enc, const float* __restrict__ WgA,
                     const float* __restrict__ WgB, const float* __restrict__ WvA,
                     const float* __restrict__ WvB, const float* __restrict__ pg_b1,
                     const float* __restrict__ pv_b1, float* __restrict__ Ag,
                     float* __restrict__ Av, float2* __restrict__ P4) {
  const int row = blockIdx.x;
  const int lane = threadIdx.x;
  __shared__ float erow[H];
  erow[lane] = enc[row * H + lane];
  __syncthreads();
  float ag = pg_b1[lane], bg = 0.f, av = pv_b1[lane], bv = 0.f;
#pragma unroll 4
  for (int k = 0; k < H; ++k) {
    float e = erow[k];
    ag += e * WgA[k * H + lane];
    bg += e * WgB[k * H + lane];
    av += e * WvA[k * H + lane];
    bv += e * WvB[k * H + lane];
  }
  Ag[row * H + lane] = ag;
  Av[row * H + lane] = av;
  int idx = (((row >> 4) * 4 + (lane >> 4)) * 4 + ((lane >> 2) & 3)) * 64 +
            (row & 15) * 4 + (lane & 3);
  P4[idx] = make_float2(bg, bv);
}

// ---------------- PAIR PARTIAL (MFMA): 2 blocks per i (j-halves), 2 waves per block.
// R4's proven register structure (VGPR~120, no spill); exp2-domain + defer-rescale.
// Emits unnormalized flash partial (m, s, ctx[64]) per block.
__global__ __launch_bounds__(128) void k_pairp(
    const float* __restrict__ enc, const float* __restrict__ Ag,
    const float* __restrict__ Av, const unsigned int* __restrict__ WF,
    const float2* __restrict__ P4, const float* __restrict__ pg_w2,
    const float* __restrict__ pg_b2, float* __restrict__ Pm, float* __restrict__ Ps,
    float* __restrict__ Pctx0, float* __restrict__ Pctx1) {
  const int bid = blockIdx.x;
  const int i = bid & (N - 1);
  const int half = bid >> 10;
  const int tid = threadIdx.x;
  const int lane = tid & 63;
  const int w = tid >> 6;  // 0/1: quarter within this half
  const int l15 = lane & 15, g4 = lane >> 4;
  const float LOG2E = 1.44269504088896f;

  bf16x8 wg[2][4], wv[2][4];
  const uint4* WF4 = (const uint4*)WF;
#pragma unroll
  for (int ks = 0; ks < 2; ++ks)
#pragma unroll
    for (int Mt = 0; Mt < 4; ++Mt) {
      wg[ks][Mt] = __builtin_bit_cast(bf16x8, WF4[(ks * 4 + Mt) * 64 + lane]);
      wv[ks][Mt] = __builtin_bit_cast(bf16x8, WF4[((2 + ks) * 4 + Mt) * 64 + lane]);
    }

  const float* encI = enc + i * H;
  const float4 ei0 = *(const float4*)(encI + g4 * 8);
  const float4 ei1 = *(const float4*)(encI + g4 * 8 + 4);
  const float4 ei2 = *(const float4*)(encI + 32 + g4 * 8);
  const float4 ei3 = *(const float4*)(encI + 32 + g4 * 8 + 4);

  f32x4 agv[4], avv[4];
  float4 w2s[4];
#pragma unroll
  for (int Mt = 0; Mt < 4; ++Mt) {
    float4 t = *(const float4*)(Ag + i * H + Mt * 16 + g4 * 4);
    agv[Mt] = f32x4{t.x, t.y, t.z, t.w};
    float4 u = *(const float4*)(Av + i * H + Mt * 16 + g4 * 4);
    avv[Mt] = f32x4{u.x, u.y, u.z, u.w};
    float4 ww = *(const float4*)(pg_w2 + Mt * 16 + g4 * 4);
    w2s[Mt] = make_float4(ww.x * LOG2E, ww.y * LOG2E, ww.z * LOG2E, ww.w * LOG2E);
  }
  const float b2g = pg_b2[0] * LOG2E;

  float m = -3.0e38f, s = 0.f;
  float ctx[16];
#pragma unroll
  for (int e = 0; e < 16; ++e) ctx[e] = 0.f;

  const int jbase = half * 512 + w * 256;
  const float* ejp = enc + (jbase + l15) * H + g4 * 8;
  float4 na = *(const float4*)(ejp);
  float4 nb = *(const float4*)(ejp + 4);
  float4 nc = *(const float4*)(ejp + 32);
  float4 nd = *(const float4*)(ejp + 36);

#pragma unroll 1
  for (int t = 0; t < 16; ++t) {
    const int j0 = jbase + t * 16;
    float4 pq[8];
#pragma unroll
    for (int Mt = 0; Mt < 4; ++Mt) {
      const float4* pp =
          (const float4*)(P4 + (size_t)((((j0 >> 4) * 4 + Mt) * 4 + g4)) * 64 + l15 * 4);
      pq[Mt * 2 + 0] = pp[0];
      pq[Mt * 2 + 1] = pp[1];
    }
    bf16x8 b0, b1;
    b0[0] = bfc(fabsf(ei0.x - na.x)); b0[1] = bfc(fabsf(ei0.y - na.y));
    b0[2] = bfc(fabsf(ei0.z - na.z)); b0[3] = bfc(fabsf(ei0.w - na.w));
    b0[4] = bfc(fabsf(ei1.x - nb.x)); b0[5] = bfc(fabsf(ei1.y - nb.y));
    b0[6] = bfc(fabsf(ei1.z - nb.z)); b0[7] = bfc(fabsf(ei1.w - nb.w));
    b1[0] = bfc(fabsf(ei2.x - nc.x)); b1[1] = bfc(fabsf(ei2.y - nc.y));
    b1[2] = bfc(fabsf(ei2.z - nc.z)); b1[3] = bfc(fabsf(ei2.w - nc.w));
    b1[4] = bfc(fabsf(ei3.x - nd.x)); b1[5] = bfc(fabsf(ei3.y - nd.y));
    b1[6] = bfc(fabsf(ei3.z - nd.z)); b1[7] = bfc(fabsf(ei3.w - nd.w));
    ejp += 16 * H;  // last-iter overread stays inside d_ws: unused
    na = *(const float4*)(ejp);
    nb = *(const float4*)(ejp + 4);
    nc = *(const float4*)(ejp + 32);
    nd = *(const float4*)(ejp + 36);

    f32x4 cg[4], cv[4];
#pragma unroll
    for (int Mt = 0; Mt < 4; ++Mt) {
      cg[Mt] = __builtin_amdgcn_mfma_f32_16x16x32_bf16(wg[0][Mt], b0, agv[Mt], 0, 0, 0);
      cg[Mt] = __builtin_amdgcn_mfma_f32_16x16x32_bf16(wg[1][Mt], b1, cg[Mt], 0, 0, 0);
      cv[Mt] = __builtin_amdgcn_mfma_f32_16x16x32_bf16(wv[0][Mt], b0, avv[Mt], 0, 0, 0);
      cv[Mt] = __builtin_amdgcn_mfma_f32_16x16x32_bf16(wv[1][Mt], b1, cv[Mt], 0, 0, 0);
    }

    // gate (log2 domain) = sum_l relu(tg[l,j]) * w2log2e[l] + b2log2e
    float gate = 0.f;
#pragma unroll
    for (int Mt = 0; Mt < 4; ++Mt) {
      gate = fmaf(fmaxf(cg[Mt][0] + pq[Mt * 2].x, 0.f), w2s[Mt].x, gate);
      gate = fmaf(fmaxf(cg[Mt][1] + pq[Mt * 2].z, 0.f), w2s[Mt].y, gate);
      gate = fmaf(fmaxf(cg[Mt][2] + pq[Mt * 2 + 1].x, 0.f), w2s[Mt].z, gate);
      gate = fmaf(fmaxf(cg[Mt][3] + pq[Mt * 2 + 1].z, 0.f), w2s[Mt].w, gate);
    }
    gate += __shfl_xor(gate, 16, 64);
    gate += __shfl_xor(gate, 32, 64);
    gate += b2g;
    if (j0 + l15 == i) gate = -3.0e38f;  // diagonal mask

    float p;
    if (__any(gate > m + 8.f)) {  // rescale only when some lane's max grew
      float mn = fmaxf(m, gate);
      float c = exp2f(m - mn);
      p = exp2f(gate - mn);
      s *= c;
      m = mn;
#pragma unroll
      for (int e = 0; e < 16; ++e) ctx[e] *= c;
    } else {
      p = exp2f(gate - m);  // bounded by 2^8
    }
    s += p;
#pragma unroll
    for (int Mt = 0; Mt < 4; ++Mt) {
      ctx[Mt * 4 + 0] = fmaf(p, fmaxf(cv[Mt][0] + pq[Mt * 2].y, 0.f), ctx[Mt * 4 + 0]);
      ctx[Mt * 4 + 1] = fmaf(p, fmaxf(cv[Mt][1] + pq[Mt * 2].w, 0.f), ctx[Mt * 4 + 1]);
      ctx[Mt * 4 + 2] = fmaf(p, fmaxf(cv[Mt][2] + pq[Mt * 2 + 1].y, 0.f), ctx[Mt * 4 + 2]);
      ctx[Mt * 4 + 3] = fmaf(p, fmaxf(cv[Mt][3] + pq[Mt * 2 + 1].w, 0.f), ctx[Mt * 4 + 3]);
    }
  }

  // in-wave flash-merge across the 16 j-columns (xor butterfly over lane&15)
#pragma unroll
  for (int off = 1; off <= 8; off <<= 1) {
    float mo = __shfl_xor(m, off, 64);
    float so = __shfl_xor(s, off, 64);
    float M2 = fmaxf(m, mo);
    float ca = exp2f(m - M2);
    float cb = exp2f(mo - M2);
    s = s * ca + so * cb;
#pragma unroll
    for (int e = 0; e < 16; ++e) {
      float co = __shfl_xor(ctx[e], off, 64);
      ctx[e] = ctx[e] * ca + co * cb;
    }
    m = M2;
  }

  __shared__ float ctxs[2][64];
  __shared__ float mss[2][2];
  if (l15 == 0) {
#pragma unroll
    for (int Mt = 0; Mt < 4; ++Mt)
#pragma unroll
      for (int r = 0; r < 4; ++r) ctxs[w][Mt * 16 + g4 * 4 + r] = ctx[Mt * 4 + r];
  }
  if (lane == 0) {
    mss[w][0] = m;
    mss[w][1] = s;
  }
  __syncthreads();

  if (w == 0) {
    float m0 = mss[0][0], s0 = mss[0][1], m1 = mss[1][0], s1 = mss[1][1];
    float M = fmaxf(m0, m1);
    float e0 = exp2f(m0 - M), e1 = exp2f(m1 - M);
    float S = s0 * e0 + s1 * e1;
    float cm = ctxs[0][lane] * e0 + ctxs[1][lane] * e1;  // unnormalized
    float* dst = half ? Pctx1 : Pctx0;
    dst[i * H + lane] = cm;
    if (lane == 0) {
      Pm[bid] = M;
      Ps[bid] = S;
    }
  }
}

// ---------------- merge two j-half partials + pv_w2 matvec + residual + LN -> enc2
__global__ void k_pmerge(const float* __restrict__ Pm, const float* __restrict__ Ps,
                         const float* __restrict__ Pctx0, const float* __restrict__ Pctx1,
                         const float* __restrict__ enc, const float* __restrict__ pv_w2,
                         const float* __restrict__ pv_b2, const float* __restrict__ lng,
                         const float* __restrict__ lnb, float* __restrict__ enc2) {
  const int i = blockIdx.x;
  const int lane = threadIdx.x;
  float m0 = Pm[i], s0 = Ps[i], m1 = Pm[N + i], s1 = Ps[N + i];
  float c0 = Pctx0[i * H + lane];
  float c1 = Pctx1[i * H + lane];  // aliases enc2[i*H+lane]; read-before-write below
  float M = fmaxf(m0, m1);
  float e0 = exp2f(m0 - M), e1 = exp2f(m1 - M);
  float S = s0 * e0 + s1 * e1;
  float cp = (c0 * e0 + c1 * e1) / S;
  float pc = pv_b2[lane];
#pragma unroll 8
  for (int k = 0; k < 64; ++k) pc += __shfl(cp, k, 64) * pv_w2[k * H + lane];
  float x = enc[i * H + lane] + pc;
  float mu = wave_reduce_sum(x) * (1.f / 64.f);
  float dd = x - mu;
  float var = wave_reduce_sum(dd * dd) * (1.f / 64.f);
  enc2[i * H + lane] = dd * rsqrtf(var + 1e-5f) * lng[lane] + lnb[lane];
}

// ---------------- column-sum stage 1: 32 blocks x 32 rows each
__global__ __launch_bounds__(256) void k_colsum(const float* __restrict__ enc2,
                                                float* __restrict__ part) {
  const int b = blockIdx.x;
  const int lane = threadIdx.x & 63, grp = threadIdx.x >> 6;
  const float* p = enc2 + (b * 32 + grp) * H + lane;
  float s = 0.f;
#pragma unroll
  for (int r = 0; r < 8; ++r) s += p[r * 4 * H];
  __shared__ float sh[4][64];
  sh[grp][lane] = s;
  __syncthreads();
  if (grp == 0) part[b * 64 + lane] = sh[0][lane] + sh[1][lane] + sh[2][lane] + sh[3][lane];
}

// ---------------- score head (graph-mean base folded in per-block)
__global__ void k_score(const float* __restrict__ enc2, const float* __restrict__ sh_w1,
                        const float* __restrict__ sh_b1, const float* __restrict__ sh_w2,
                        const float* __restrict__ sh_b2, const float* __restrict__ part,
                        float* __restrict__ out) {
  const int row = blockIdx.x;
  const int lane = threadIdx.x;
  __shared__ float erow[H];
  erow[lane] = enc2[row * H + lane];
  __syncthreads();
  float g = 0.f;
#pragma unroll
  for (int p = 0; p < 32; ++p) g += part[p * 64 + lane];
  g *= (1.f / N);
  float t = sh_b1[lane];
#pragma unroll 8
  for (int k = 0; k < 64; ++k) {
    t += erow[k] * sh_w1[k * H + lane];
    t += __shfl(g, k, 64) * sh_w1[(64 + k) * H + lane];
  }
  t = fmaxf(t, 0.f);
  float prt = t * sh_w2[lane];
  float sum = wave_reduce_sum(prt);
  if (lane == 0) out[row] = sum + sh_b2[0];
}

extern "C" void kernel_launch(void* const* d_in, const int* in_sizes, int n_in,
                              void* d_out, int out_size, void* d_ws, size_t ws_size,
                              hipStream_t stream) {
  const float* feat = (const float*)d_in[0];
  const float* ip_w1 = (const float*)d_in[1];
  const float* ip_b1 = (const float*)d_in[2];
  const float* ip_ln_g = (const float*)d_in[3];
  const float* ip_ln_b = (const float*)d_in[4];
  const float* ip_w2 = (const float*)d_in[5];
  const float* ip_b2 = (const float*)d_in[6];
  const float* attn_in_w = (const float*)d_in[7];
  const float* attn_in_b = (const float*)d_in[8];
  const float* attn_out_w = (const float*)d_in[9];
  const float* attn_out_b = (const float*)d_in[10];
  const float* attn_ln_g = (const float*)d_in[11];
  const float* attn_ln_b = (const float*)d_in[12];
  const float* pg_w1 = (const float*)d_in[13];
  const float* pg_b1 = (const float*)d_in[14];
  const float* pg_w2 = (const float*)d_in[15];
  const float* pg_b2 = (const float*)d_in[16];
  const float* pv_w1 = (const float*)d_in[17];
  const float* pv_b1 = (const float*)d_in[18];
  const float* pv_w2 = (const float*)d_in[19];
  const float* pv_b2 = (const float*)d_in[20];
  const float* ctx_ln_g = (const float*)d_in[21];
  const float* ctx_ln_b = (const float*)d_in[22];
  const float* sh_w1 = (const float*)d_in[23];
  const float* sh_b1 = (const float*)d_in[24];
  const float* sh_w2 = (const float*)d_in[25];
  const float* sh_b2 = (const float*)d_in[26];

  float* ws = (float*)d_ws;
  float* h = ws;                        // 0      .. 65536   (dead after k_attn_out)
  float* Qh = ws + 65536;               // 65536  .. 131072
  float* Kh = ws + 131072;              // 131072 .. 196608
  float* Vh = ws + 196608;              // 196608 .. 262144
  float* o = ws + 262144;               // 262144 .. 327680
  float* enc = ws + 327680;             // 327680 .. 393216
  float* enc2 = ws + 393216;            // 393216 .. 458752
  float2* P4 = (float2*)(ws + 65536);   // reuse Qh+Kh (128K floats)
  float* Ag = ws + 196608;              // reuse Vh
  float* Av = ws + 262144;              // reuse o
  float* Pctx0 = ws;                    // reuse h (64K floats)
  float* Pctx1 = enc2;                  // merge reads partial then overwrites same slot
  float* WgA = ws + 458752;             // 4096 each
  float* WgB = ws + 462848;
  float* WvA = ws + 466944;
  float* WvB = ws + 471040;
  unsigned int* WF = (unsigned int*)(ws + 475136);  // 4096 u32
  float* part = ws + 479232;            // 2048
  float* Pm = ws + 481280;              // 2048
  float* Ps = ws + 483328;              // 2048
  float* out = (float*)d_out;

  k_input_qkv<<<N, 64, 0, stream>>>(feat, ip_w1, ip_b1, ip_ln_g, ip_ln_b, ip_w2, ip_b2,
                                    attn_in_w, attn_in_b, h, Qh, Kh, Vh);
  k_attn2<<<512, 256, 0, stream>>>(Qh, Kh, Vh, o);
  k_attn_out<<<N, 64, 0, stream>>>(o, attn_out_w, attn_out_b, h, attn_ln_g, attn_ln_b, enc);
  k_prep<<<20, 256, 0, stream>>>(pg_w1, pv_w1, WgA, WgB, WvA, WvB, WF);
  k_ab<<<N, 64, 0, stream>>>(enc, WgA, WgB, WvA, WvB, pg_b1, pv_b1, Ag, Av, P4);
  k_pairp<<<2 * N, 128, 0, stream>>>(enc, Ag, Av, WF, P4, pg_w2, pg_b2, Pm, Ps, Pctx0, Pctx1);
  k_pmerge<<<N, 64, 0, stream>>>(Pm, Ps, Pctx0, Pctx1, enc, pv_w2, pv_b2, ctx_ln_g,
                                 ctx_ln_b, enc2);
  k_colsum<<<32, 256, 0, stream>>>(enc2, part);
  k_score<<<N, 64, 0, stream>>>(enc2, sh_w1, sh_b1, sh_w2, sh_b2, part, out);
}

// Round 8
// 120.213 us; speedup vs baseline: 3.0731x; 1.0802x over previous
//
#include <hip/hip_runtime.h>
#include <hip/hip_bf16.h>
#include <math.h>

#define N 1024
#define F 256
#define H 64

typedef __attribute__((ext_vector_type(8))) short bf16x8;
typedef __attribute__((ext_vector_type(4))) float f32x4;

__device__ __forceinline__ float wave_reduce_sum(float v) {
#pragma unroll
  for (int off = 32; off; off >>= 1) v += __shfl_xor(v, off, 64);
  return v;
}

__device__ __forceinline__ short bfc(float x) {
  __hip_bfloat16 h = __float2bfloat16(x);
  return __builtin_bit_cast(short, h);
}

__device__ __forceinline__ unsigned int bfpack(float a, float b) {
  return (unsigned int)(unsigned short)bfc(a) | ((unsigned int)(unsigned short)bfc(b) << 16);
}

// ---------------- FUSED input_proj + qkv: Linear->LN->ReLU->Linear->ReLU->qkv proj
__global__ void k_input_qkv(const float* __restrict__ feat,
                            const float* __restrict__ w1, const float* __restrict__ b1,
                            const float* __restrict__ lng, const float* __restrict__ lnb,
                            const float* __restrict__ w2, const float* __restrict__ b2,
                            const float* __restrict__ aw, const float* __restrict__ abias,
                            float* __restrict__ h, float* __restrict__ Qh,
                            float* __restrict__ Kh, float* __restrict__ Vh) {
  const int row = blockIdx.x;
  const int lane = threadIdx.x;  // 0..63
  __shared__ float frow[F];
#pragma unroll
  for (int c = 0; c < 4; ++c) frow[c * 64 + lane] = feat[row * F + c * 64 + lane];
  __syncthreads();
  float acc = b1[lane];
#pragma unroll 8
  for (int k = 0; k < F; ++k) acc += frow[k] * w1[k * H + lane];
  float mu = wave_reduce_sum(acc) * (1.f / 64.f);
  float d = acc - mu;
  float var = wave_reduce_sum(d * d) * (1.f / 64.f);
  float y = d * rsqrtf(var + 1e-5f) * lng[lane] + lnb[lane];
  y = fmaxf(y, 0.f);
  __shared__ float yrow[H];
  yrow[lane] = y;
  __syncthreads();
  float acc2 = b2[lane];
#pragma unroll 8
  for (int k = 0; k < H; ++k) acc2 += yrow[k] * w2[k * H + lane];
  float hv = fmaxf(acc2, 0.f);
  h[row * H + lane] = hv;
  __shared__ float hrow[H];
  hrow[lane] = hv;
  __syncthreads();
  float a0 = abias[lane], a1 = abias[64 + lane], a2 = abias[128 + lane];
#pragma unroll 8
  for (int k = 0; k < H; ++k) {
    float hk = hrow[k];
    a0 += hk * aw[k * 192 + lane];
    a1 += hk * aw[k * 192 + 64 + lane];
    a2 += hk * aw[k * 192 + 128 + lane];
  }
  const int base = (lane >> 4) * (N * 16) + row * 16 + (lane & 15);
  Qh[base] = a0;
  Kh[base] = a1;
  Vh[base] = a2;
}

// ---------------- attention v3: 4 q-rows x 64 j-slots per block; wave owns one q-row.
// Grid 1024 (4 heads x 256) -> 4096 waves = 4/SIMD.
__global__ __launch_bounds__(256) void k_attn2(const float* __restrict__ Qh,
                                               const float* __restrict__ Kh,
                                               const float* __restrict__ Vh,
                                               float* __restrict__ o) {
  const int head = blockIdx.x >> 8;
  const int i0 = (blockIdx.x & 255) * 4;
  const int tid = threadIdx.x;
  const int q2 = tid >> 6, js = tid & 63;
  const int i = i0 + q2;

  const float* qp = Qh + head * (N * 16) + i * 16;
  const float4 q0 = *(const float4*)(qp);
  const float4 q1 = *(const float4*)(qp + 4);
  const float4 q2v = *(const float4*)(qp + 8);
  const float4 q3 = *(const float4*)(qp + 12);
  const float* kb = Kh + head * (N * 16);
  const float* vb = Vh + head * (N * 16);

  float m = -3.0e38f, s = 0.f;
  float4 c0 = {0, 0, 0, 0}, c1 = {0, 0, 0, 0}, c2 = {0, 0, 0, 0}, c3 = {0, 0, 0, 0};

  int j = js;
  const float* kp = kb + j * 16;
  const float* vp = vb + j * 16;
  float4 k0 = *(const float4*)(kp), k1 = *(const float4*)(kp + 4);
  float4 k2 = *(const float4*)(kp + 8), k3 = *(const float4*)(kp + 12);
  float4 v0 = *(const float4*)(vp), v1 = *(const float4*)(vp + 4);
  float4 v2 = *(const float4*)(vp + 8), v3 = *(const float4*)(vp + 12);

#pragma unroll 1
  for (int t = 0; t < 16; ++t) {
    const int jn = (j + 64) & (N - 1);  // last-iter wrap: in-bounds, result unused
    const float* kpn = kb + jn * 16;
    const float* vpn = vb + jn * 16;
    float4 nk0 = *(const float4*)(kpn), nk1 = *(const float4*)(kpn + 4);
    float4 nk2 = *(const float4*)(kpn + 8), nk3 = *(const float4*)(kpn + 12);
    float4 nv0 = *(const float4*)(vpn), nv1 = *(const float4*)(vpn + 4);
    float4 nv2 = *(const float4*)(vpn + 8), nv3 = *(const float4*)(vpn + 12);

    float sc = q0.x * k0.x + q0.y * k0.y + q0.z * k0.z + q0.w * k0.w;
    sc += q1.x * k1.x + q1.y * k1.y + q1.z * k1.z + q1.w * k1.w;
    sc += q2v.x * k2.x + q2v.y * k2.y + q2v.z * k2.z + q2v.w * k2.w;
    sc += q3.x * k3.x + q3.y * k3.y + q3.z * k3.z + q3.w * k3.w;
    sc *= 0.25f;  // 1/sqrt(16)

    float mn = fmaxf(m, sc);
    float cc = __expf(m - mn);
    float p = __expf(sc - mn);
    s = s * cc + p;
    m = mn;
    c0.x = c0.x * cc + p * v0.x; c0.y = c0.y * cc + p * v0.y;
    c0.z = c0.z * cc + p * v0.z; c0.w = c0.w * cc + p * v0.w;
    c1.x = c1.x * cc + p * v1.x; c1.y = c1.y * cc + p * v1.y;
    c1.z = c1.z * cc + p * v1.z; c1.w = c1.w * cc + p * v1.w;
    c2.x = c2.x * cc + p * v2.x; c2.y = c2.y * cc + p * v2.y;
    c2.z = c2.z * cc + p * v2.z; c2.w = c2.w * cc + p * v2.w;
    c3.x = c3.x * cc + p * v3.x; c3.y = c3.y * cc + p * v3.y;
    c3.z = c3.z * cc + p * v3.z; c3.w = c3.w * cc + p * v3.w;

    k0 = nk0; k1 = nk1; k2 = nk2; k3 = nk3;
    v0 = nv0; v1 = nv1; v2 = nv2; v3 = nv3;
    j = jn;
  }

  // merge (m,s) across the whole wave (one q-row per wave)
  float M = m, S = s;
#pragma unroll
  for (int off = 32; off; off >>= 1) {
    float Mo = __shfl_xor(M, off, 64);
    float So = __shfl_xor(S, off, 64);
    float Mn = fmaxf(M, Mo);
    S = S * __expf(M - Mn) + So * __expf(Mo - Mn);
    M = Mn;
  }
  const float wgt = __expf(m - M) / S;

  __shared__ float lds[4][64][17];
  float* lp = &lds[q2][js][0];
  lp[0] = c0.x * wgt;  lp[1] = c0.y * wgt;  lp[2] = c0.z * wgt;  lp[3] = c0.w * wgt;
  lp[4] = c1.x * wgt;  lp[5] = c1.y * wgt;  lp[6] = c1.z * wgt;  lp[7] = c1.w * wgt;
  lp[8] = c2.x * wgt;  lp[9] = c2.y * wgt;  lp[10] = c2.z * wgt; lp[11] = c2.w * wgt;
  lp[12] = c3.x * wgt; lp[13] = c3.y * wgt; lp[14] = c3.z * wgt; lp[15] = c3.w * wgt;
  __syncthreads();

  if (tid < 64) {
    const int q = tid >> 4, d = tid & 15;
    float sum = 0.f;
#pragma unroll
    for (int k = 0; k < 64; ++k) sum += lds[q][k][d];
    o[(i0 + q) * H + head * 16 + d] = sum;
  }
}

// ---------------- attn out proj + residual + LN -> enc
__global__ void k_attn_out(const float* __restrict__ o, const float* __restrict__ w,
                           const float* __restrict__ b, const float* __restrict__ h,
                           const float* __restrict__ lng, const float* __restrict__ lnb,
                           float* __restrict__ enc) {
  const int row = blockIdx.x;
  const int lane = threadIdx.x;
  __shared__ float orow[H];
  orow[lane] = o[row * H + lane];
  __syncthreads();
  float a = b[lane];
#pragma unroll 8
  for (int k = 0; k < H; ++k) a += orow[k] * w[k * H + lane];
  float x = h[row * H + lane] + a;
  float mu = wave_reduce_sum(x) * (1.f / 64.f);
  float d = x - mu;
  float var = wave_reduce_sum(d * d) * (1.f / 64.f);
  enc[row * H + lane] = d * rsqrtf(var + 1e-5f) * lng[lane] + lnb[lane];
}

// ---------------- MERGED prep: blocks 0..15 = combos; blocks 16..19 = W4^T MFMA frags
__global__ __launch_bounds__(256) void k_prep(const float* __restrict__ pg1,
                                              const float* __restrict__ pv1,
                                              float* __restrict__ WgA, float* __restrict__ WgB,
                                              float* __restrict__ WvA, float* __restrict__ WvB,
                                              unsigned int* __restrict__ WF) {
  const int blk = blockIdx.x;
  if (blk < 16) {
    int idx = blk * 256 + threadIdx.x;  // 0..4095 == k*64+l
    float g1 = pg1[idx];
    float g2 = pg1[4096 + idx];
    float g3 = pg1[8192 + idx];
    WgA[idx] = g1 + g3;
    WgB[idx] = g2 - g3;
    float v1 = pv1[idx];
    float v2 = pv1[4096 + idx];
    float v3 = pv1[8192 + idx];
    WvA[idx] = v1 + v3;
    WvB[idx] = v2 - v3;
  } else {
    const int sub = threadIdx.x >> 6;
    const int lane = threadIdx.x & 63;
    const int b = (blk - 16) * 4 + sub;  // 0..15 = mat*8 + ks*4 + Mt
    const float* W = (b & 8) ? pv1 : pg1;
    const int Mt = b & 3;
    const int ks = (b >> 2) & 1;
    const int l = Mt * 16 + (lane & 15);
    const int kb = 192 + ks * 32 + (lane >> 4) * 8;  // |diff| block = rows 192..255
    uint4 o;
    o.x = bfpack(W[(kb + 0) * H + l], W[(kb + 1) * H + l]);
    o.y = bfpack(W[(kb + 2) * H + l], W[(kb + 3) * H + l]);
    o.z = bfpack(W[(kb + 4) * H + l], W[(kb + 5) * H + l]);
    o.w = bfpack(W[(kb + 6) * H + l], W[(kb + 7) * H + l]);
    ((uint4*)WF)[b * 64 + lane] = o;
  }
}

// ---------------- per-row projections: Ag/Av (bias folded) + SPLIT transposed Bg/Bv
// Pg/Pv element (jt,Mt,g,j15,r) = B*[j, l] with j=jt*16+j15, l=Mt*16+g*4+r
__global__ void k_ab(const float* __restrict__ enc, const float* __restrict__ WgA,
                     const float* __restrict__ WgB, const float* __restrict__ WvA,
                     const float* __restrict__ WvB, const float* __restrict__ pg_b1,
                     const float* __restrict__ pv_b1, float* __restrict__ Ag,
                     float* __restrict__ Av, float* __restrict__ Pg,
                     float* __restrict__ Pv) {
  const int row = blockIdx.x;
  const int lane = threadIdx.x;
  __shared__ float erow[H];
  erow[lane] = enc[row * H + lane];
  __syncthreads();
  float ag = pg_b1[lane], bg = 0.f, av = pv_b1[lane], bv = 0.f;
#pragma unroll 4
  for (int k = 0; k < H; ++k) {
    float e = erow[k];
    ag += e * WgA[k * H + lane];
    bg += e * WgB[k * H + lane];
    av += e * WvA[k * H + lane];
    bv += e * WvB[k * H + lane];
  }
  Ag[row * H + lane] = ag;
  Av[row * H + lane] = av;
  int idx = (((row >> 4) * 4 + (lane >> 4)) * 4 + ((lane >> 2) & 3)) * 64 +
            (row & 15) * 4 + (lane & 3);
  Pg[idx] = bg;
  Pv[idx] = bv;
}

// ---------------- PAIR PARTIAL (MFMA): 2 blocks per i (j-halves), 2 waves per block.
// v3: split Pg/Pv loads (Pv issued after MFMAs, latency hidden under gate epilogue),
// tree-reduced gate (4 indep chains), exp2-domain, defer-rescale. Target VGPR <= 128.
__global__ __launch_bounds__(128) void k_pairp(
    const float* __restrict__ enc, const float* __restrict__ Ag,
    const float* __restrict__ Av, const unsigned int* __restrict__ WF,
    const float* __restrict__ Pg, const float* __restrict__ Pv,
    const float* __restrict__ pg_w2, const float* __restrict__ pg_b2,
    float* __restrict__ Pm, float* __restrict__ Ps,
    float* __restrict__ Pctx0, float* __restrict__ Pctx1) {
  const int bid = blockIdx.x;
  const int i = bid & (N - 1);
  const int half = bid >> 10;
  const int tid = threadIdx.x;
  const int lane = tid & 63;
  const int w = tid >> 6;  // 0/1: quarter within this half
  const int l15 = lane & 15, g4 = lane >> 4;
  const float LOG2E = 1.44269504088896f;

  bf16x8 wg[2][4], wv[2][4];
  const uint4* WF4 = (const uint4*)WF;
#pragma unroll
  for (int ks = 0; ks < 2; ++ks)
#pragma unroll
    for (int Mt = 0; Mt < 4; ++Mt) {
      wg[ks][Mt] = __builtin_bit_cast(bf16x8, WF4[(ks * 4 + Mt) * 64 + lane]);
      wv[ks][Mt] = __builtin_bit_cast(bf16x8, WF4[((2 + ks) * 4 + Mt) * 64 + lane]);
    }

  const float* encI = enc + i * H;
  const float4 ei0 = *(const float4*)(encI + g4 * 8);
  const float4 ei1 = *(const float4*)(encI + g4 * 8 + 4);
  const float4 ei2 = *(const float4*)(encI + 32 + g4 * 8);
  const float4 ei3 = *(const float4*)(encI + 32 + g4 * 8 + 4);

  f32x4 agv[4], avv[4];
  float4 w2s[4];
#pragma unroll
  for (int Mt = 0; Mt < 4; ++Mt) {
    float4 t = *(const float4*)(Ag + i * H + Mt * 16 + g4 * 4);
    agv[Mt] = f32x4{t.x, t.y, t.z, t.w};
    float4 u = *(const float4*)(Av + i * H + Mt * 16 + g4 * 4);
    avv[Mt] = f32x4{u.x, u.y, u.z, u.w};
    float4 ww = *(const float4*)(pg_w2 + Mt * 16 + g4 * 4);
    w2s[Mt] = make_float4(ww.x * LOG2E, ww.y * LOG2E, ww.z * LOG2E, ww.w * LOG2E);
  }
  const float b2g = pg_b2[0] * LOG2E;

  float m = -3.0e38f, s = 0.f;
  float ctx[16];
#pragma unroll
  for (int e = 0; e < 16; ++e) ctx[e] = 0.f;

  const int jbase = half * 512 + w * 256;
  const float* ejp = enc + (jbase + l15) * H + g4 * 8;
  float4 na = *(const float4*)(ejp);
  float4 nb = *(const float4*)(ejp + 4);
  float4 nc = *(const float4*)(ejp + 32);
  float4 nd = *(const float4*)(ejp + 36);

#pragma unroll 1
  for (int t = 0; t < 16; ++t) {
    const int j0 = jbase + t * 16;
    const int pbase = ((j0 >> 4) * 16 + g4) * 64 + l15 * 4;
    // gate-side B terms (needed right after cg MFMAs)
    float4 pg0 = *(const float4*)(Pg + pbase);
    float4 pg1 = *(const float4*)(Pg + pbase + 256);
    float4 pg2 = *(const float4*)(Pg + pbase + 512);
    float4 pg3 = *(const float4*)(Pg + pbase + 768);

    bf16x8 b0, b1;
    b0[0] = bfc(fabsf(ei0.x - na.x)); b0[1] = bfc(fabsf(ei0.y - na.y));
    b0[2] = bfc(fabsf(ei0.z - na.z)); b0[3] = bfc(fabsf(ei0.w - na.w));
    b0[4] = bfc(fabsf(ei1.x - nb.x)); b0[5] = bfc(fabsf(ei1.y - nb.y));
    b0[6] = bfc(fabsf(ei1.z - nb.z)); b0[7] = bfc(fabsf(ei1.w - nb.w));
    b1[0] = bfc(fabsf(ei2.x - nc.x)); b1[1] = bfc(fabsf(ei2.y - nc.y));
    b1[2] = bfc(fabsf(ei2.z - nc.z)); b1[3] = bfc(fabsf(ei2.w - nc.w));
    b1[4] = bfc(fabsf(ei3.x - nd.x)); b1[5] = bfc(fabsf(ei3.y - nd.y));
    b1[6] = bfc(fabsf(ei3.z - nd.z)); b1[7] = bfc(fabsf(ei3.w - nd.w));
    ejp += 16 * H;  // last-iter overread stays inside d_ws: unused
    na = *(const float4*)(ejp);
    nb = *(const float4*)(ejp + 4);
    nc = *(const float4*)(ejp + 32);
    nd = *(const float4*)(ejp + 36);

    f32x4 cg[4], cv[4];
#pragma unroll
    for (int Mt = 0; Mt < 4; ++Mt) {
      cg[Mt] = __builtin_amdgcn_mfma_f32_16x16x32_bf16(wg[0][Mt], b0, agv[Mt], 0, 0, 0);
      cg[Mt] = __builtin_amdgcn_mfma_f32_16x16x32_bf16(wg[1][Mt], b1, cg[Mt], 0, 0, 0);
      cv[Mt] = __builtin_amdgcn_mfma_f32_16x16x32_bf16(wv[0][Mt], b0, avv[Mt], 0, 0, 0);
      cv[Mt] = __builtin_amdgcn_mfma_f32_16x16x32_bf16(wv[1][Mt], b1, cv[Mt], 0, 0, 0);
    }

    // val-side B terms: issue now, consumed after gate epilogue (latency hidden)
    float4 pv0 = *(const float4*)(Pv + pbase);
    float4 pv1 = *(const float4*)(Pv + pbase + 256);
    float4 pv2 = *(const float4*)(Pv + pbase + 512);
    float4 pv3 = *(const float4*)(Pv + pbase + 768);

    // gate (log2 domain): 4 independent fma chains, then pairwise sum
    float ga = fmaxf(cg[0][0] + pg0.x, 0.f) * w2s[0].x;
    float gb = fmaxf(cg[0][1] + pg0.y, 0.f) * w2s[0].y;
    float gc = fmaxf(cg[0][2] + pg0.z, 0.f) * w2s[0].z;
    float gd = fmaxf(cg[0][3] + pg0.w, 0.f) * w2s[0].w;
    ga = fmaf(fmaxf(cg[1][0] + pg1.x, 0.f), w2s[1].x, ga);
    gb = fmaf(fmaxf(cg[1][1] + pg1.y, 0.f), w2s[1].y, gb);
    gc = fmaf(fmaxf(cg[1][2] + pg1.z, 0.f), w2s[1].z, gc);
    gd = fmaf(fmaxf(cg[1][3] + pg1.w, 0.f), w2s[1].w, gd);
    ga = fmaf(fmaxf(cg[2][0] + pg2.x, 0.f), w2s[2].x, ga);
    gb = fmaf(fmaxf(cg[2][1] + pg2.y, 0.f), w2s[2].y, gb);
    gc = fmaf(fmaxf(cg[2][2] + pg2.z, 0.f), w2s[2].z, gc);
    gd = fmaf(fmaxf(cg[2][3] + pg2.w, 0.f), w2s[2].w, gd);
    ga = fmaf(fmaxf(cg[3][0] + pg3.x, 0.f), w2s[3].x, ga);
    gb = fmaf(fmaxf(cg[3][1] + pg3.y, 0.f), w2s[3].y, gb);
    gc = fmaf(fmaxf(cg[3][2] + pg3.z, 0.f), w2s[3].z, gc);
    gd = fmaf(fmaxf(cg[3][3] + pg3.w, 0.f), w2s[3].w, gd);
    float gate = (ga + gb) + (gc + gd);
    gate += __shfl_xor(gate, 16, 64);
    gate += __shfl_xor(gate, 32, 64);
    gate += b2g;
    if (j0 + l15 == i) gate = -3.0e38f;  // diagonal mask

    float p;
    if (__any(gate > m + 8.f)) {  // rescale only when some lane's max grew
      float mn = fmaxf(m, gate);
      float c = exp2f(m - mn);
      p = exp2f(gate - mn);
      s *= c;
      m = mn;
#pragma unroll
      for (int e = 0; e < 16; ++e) ctx[e] *= c;
    } else {
      p = exp2f(gate - m);  // bounded by 2^8
    }
    s += p;
    ctx[0]  = fmaf(p, fmaxf(cv[0][0] + pv0.x, 0.f), ctx[0]);
    ctx[1]  = fmaf(p, fmaxf(cv[0][1] + pv0.y, 0.f), ctx[1]);
    ctx[2]  = fmaf(p, fmaxf(cv[0][2] + pv0.z, 0.f), ctx[2]);
    ctx[3]  = fmaf(p, fmaxf(cv[0][3] + pv0.w, 0.f), ctx[3]);
    ctx[4]  = fmaf(p, fmaxf(cv[1][0] + pv1.x, 0.f), ctx[4]);
    ctx[5]  = fmaf(p, fmaxf(cv[1][1] + pv1.y, 0.f), ctx[5]);
    ctx[6]  = fmaf(p, fmaxf(cv[1][2] + pv1.z, 0.f), ctx[6]);
    ctx[7]  = fmaf(p, fmaxf(cv[1][3] + pv1.w, 0.f), ctx[7]);
    ctx[8]  = fmaf(p, fmaxf(cv[2][0] + pv2.x, 0.f), ctx[8]);
    ctx[9]  = fmaf(p, fmaxf(cv[2][1] + pv2.y, 0.f), ctx[9]);
    ctx[10] = fmaf(p, fmaxf(cv[2][2] + pv2.z, 0.f), ctx[10]);
    ctx[11] = fmaf(p, fmaxf(cv[2][3] + pv2.w, 0.f), ctx[11]);
    ctx[12] = fmaf(p, fmaxf(cv[3][0] + pv3.x, 0.f), ctx[12]);
    ctx[13] = fmaf(p, fmaxf(cv[3][1] + pv3.y, 0.f), ctx[13]);
    ctx[14] = fmaf(p, fmaxf(cv[3][2] + pv3.z, 0.f), ctx[14]);
    ctx[15] = fmaf(p, fmaxf(cv[3][3] + pv3.w, 0.f), ctx[15]);
  }

  // in-wave flash-merge across the 16 j-columns (xor butterfly over lane&15)
#pragma unroll
  for (int off = 1; off <= 8; off <<= 1) {
    float mo = __shfl_xor(m, off, 64);
    float so = __shfl_xor(s, off, 64);
    float M2 = fmaxf(m, mo);
    float ca = exp2f(m - M2);
    float cb = exp2f(mo - M2);
    s = s * ca + so * cb;
#pragma unroll
    for (int e = 0; e < 16; ++e) {
      float co = __shfl_xor(ctx[e], off, 64);
      ctx[e] = ctx[e] * ca + co * cb;
    }
    m = M2;
  }

  __shared__ float ctxs[2][64];
  __shared__ float mss[2][2];
  if (l15 == 0) {
#pragma unroll
    for (int Mt = 0; Mt < 4; ++Mt)
#pragma unroll
      for (int r = 0; r < 4; ++r) ctxs[w][Mt * 16 + g4 * 4 + r] = ctx[Mt * 4 + r];
  }
  if (lane == 0) {
    mss[w][0] = m;
    mss[w][1] = s;
  }
  __syncthreads();

  if (w == 0) {
    float m0 = mss[0][0], s0 = mss[0][1], m1 = mss[1][0], s1 = mss[1][1];
    float M = fmaxf(m0, m1);
    float e0 = exp2f(m0 - M), e1 = exp2f(m1 - M);
    float S = s0 * e0 + s1 * e1;
    float cm = ctxs[0][lane] * e0 + ctxs[1][lane] * e1;  // unnormalized
    float* dst = half ? Pctx1 : Pctx0;
    dst[i * H + lane] = cm;
    if (lane == 0) {
      Pm[bid] = M;
      Ps[bid] = S;
    }
  }
}

// ---------------- merge two j-half partials + pv_w2 matvec + residual + LN -> enc2
__global__ void k_pmerge(const float* __restrict__ Pm, const float* __restrict__ Ps,
                         const float* __restrict__ Pctx0, const float* __restrict__ Pctx1,
                         const float* __restrict__ enc, const float* __restrict__ pv_w2,
                         const float* __restrict__ pv_b2, const float* __restrict__ lng,
                         const float* __restrict__ lnb, float* __restrict__ enc2) {
  const int i = blockIdx.x;
  const int lane = threadIdx.x;
  float m0 = Pm[i], s0 = Ps[i], m1 = Pm[N + i], s1 = Ps[N + i];
  float c0 = Pctx0[i * H + lane];
  float c1 = Pctx1[i * H + lane];  // aliases enc2[i*H+lane]; read-before-write below
  float M = fmaxf(m0, m1);
  float e0 = exp2f(m0 - M), e1 = exp2f(m1 - M);
  float S = s0 * e0 + s1 * e1;
  float cp = (c0 * e0 + c1 * e1) / S;
  float pc = pv_b2[lane];
#pragma unroll 8
  for (int k = 0; k < 64; ++k) pc += __shfl(cp, k, 64) * pv_w2[k * H + lane];
  float x = enc[i * H + lane] + pc;
  float mu = wave_reduce_sum(x) * (1.f / 64.f);
  float dd = x - mu;
  float var = wave_reduce_sum(dd * dd) * (1.f / 64.f);
  enc2[i * H + lane] = dd * rsqrtf(var + 1e-5f) * lng[lane] + lnb[lane];
}

// ---------------- column-sum stage 1: 32 blocks x 32 rows each
__global__ __launch_bounds__(256) void k_colsum(const float* __restrict__ enc2,
                                                float* __restrict__ part) {
  const int b = blockIdx.x;
  const int lane = threadIdx.x & 63, grp = threadIdx.x >> 6;
  const float* p = enc2 + (b * 32 + grp) * H + lane;
  float s = 0.f;
#pragma unroll
  for (int r = 0; r < 8; ++r) s += p[r * 4 * H];
  __shared__ float sh[4][64];
  sh[grp][lane] = s;
  __syncthreads();
  if (grp == 0) part[b * 64 + lane] = sh[0][lane] + sh[1][lane] + sh[2][lane] + sh[3][lane];
}

// ---------------- score head (graph-mean base folded in per-block)
__global__ void k_score(const float* __restrict__ enc2, const float* __restrict__ sh_w1,
                        const float* __restrict__ sh_b1, const float* __restrict__ sh_w2,
                        const float* __restrict__ sh_b2, const float* __restrict__ part,
                        float* __restrict__ out) {
  const int row = blockIdx.x;
  const int lane = threadIdx.x;
  __shared__ float erow[H];
  erow[lane] = enc2[row * H + lane];
  __syncthreads();
  float g = 0.f;
#pragma unroll
  for (int p = 0; p < 32; ++p) g += part[p * 64 + lane];
  g *= (1.f / N);
  float t = sh_b1[lane];
#pragma unroll 8
  for (int k = 0; k < 64; ++k) {
    t += erow[k] * sh_w1[k * H + lane];
    t += __shfl(g, k, 64) * sh_w1[(64 + k) * H + lane];
  }
  t = fmaxf(t, 0.f);
  float prt = t * sh_w2[lane];
  float sum = wave_reduce_sum(prt);
  if (lane == 0) out[row] = sum + sh_b2[0];
}

extern "C" void kernel_launch(void* const* d_in, const int* in_sizes, int n_in,
                              void* d_out, int out_size, void* d_ws, size_t ws_size,
                              hipStream_t stream) {
  const float* feat = (const float*)d_in[0];
  const float* ip_w1 = (const float*)d_in[1];
  const float* ip_b1 = (const float*)d_in[2];
  const float* ip_ln_g = (const float*)d_in[3];
  const float* ip_ln_b = (const float*)d_in[4];
  const float* ip_w2 = (const float*)d_in[5];
  const float* ip_b2 = (const float*)d_in[6];
  const float* attn_in_w = (const float*)d_in[7];
  const float* attn_in_b = (const float*)d_in[8];
  const float* attn_out_w = (const float*)d_in[9];
  const float* attn_out_b = (const float*)d_in[10];
  const float* attn_ln_g = (const float*)d_in[11];
  const float* attn_ln_b = (const float*)d_in[12];
  const float* pg_w1 = (const float*)d_in[13];
  const float* pg_b1 = (const float*)d_in[14];
  const float* pg_w2 = (const float*)d_in[15];
  const float* pg_b2 = (const float*)d_in[16];
  const float* pv_w1 = (const float*)d_in[17];
  const float* pv_b1 = (const float*)d_in[18];
  const float* pv_w2 = (const float*)d_in[19];
  const float* pv_b2 = (const float*)d_in[20];
  const float* ctx_ln_g = (const float*)d_in[21];
  const float* ctx_ln_b = (const float*)d_in[22];
  const float* sh_w1 = (const float*)d_in[23];
  const float* sh_b1 = (const float*)d_in[24];
  const float* sh_w2 = (const float*)d_in[25];
  const float* sh_b2 = (const float*)d_in[26];

  float* ws = (float*)d_ws;
  float* h = ws;                        // 0      .. 65536   (dead after k_attn_out)
  float* Qh = ws + 65536;               // 65536  .. 131072
  float* Kh = ws + 131072;              // 131072 .. 196608
  float* Vh = ws + 196608;              // 196608 .. 262144
  float* o = ws + 262144;               // 262144 .. 327680
  float* enc = ws + 327680;             // 327680 .. 393216
  float* enc2 = ws + 393216;            // 393216 .. 458752
  float* Pg = ws + 65536;               // reuse Qh (64K floats)
  float* Pv = ws + 131072;              // reuse Kh (64K floats)
  float* Ag = ws + 196608;              // reuse Vh
  float* Av = ws + 262144;              // reuse o
  float* Pctx0 = ws;                    // reuse h (64K floats)
  float* Pctx1 = enc2;                  // merge reads partial then overwrites same slot
  float* WgA = ws + 458752;             // 4096 each
  float* WgB = ws + 462848;
  float* WvA = ws + 466944;
  float* WvB = ws + 471040;
  unsigned int* WF = (unsigned int*)(ws + 475136);  // 4096 u32
  float* part = ws + 479232;            // 2048
  float* Pm = ws + 481280;              // 2048
  float* Ps = ws + 483328;              // 2048
  float* out = (float*)d_out;

  k_input_qkv<<<N, 64, 0, stream>>>(feat, ip_w1, ip_b1, ip_ln_g, ip_ln_b, ip_w2, ip_b2,
                                    attn_in_w, attn_in_b, h, Qh, Kh, Vh);
  k_attn2<<<1024, 256, 0, stream>>>(Qh, Kh, Vh, o);
  k_attn_out<<<N, 64, 0, stream>>>(o, attn_out_w, attn_out_b, h, attn_ln_g, attn_ln_b, enc);
  k_prep<<<20, 256, 0, stream>>>(pg_w1, pv_w1, WgA, WgB, WvA, WvB, WF);
  k_ab<<<N, 64, 0, stream>>>(enc, WgA, WgB, WvA, WvB, pg_b1, pv_b1, Ag, Av, Pg, Pv);
  k_pairp<<<2 * N, 128, 0, stream>>>(enc, Ag, Av, WF, Pg, Pv, pg_w2, pg_b2, Pm, Ps,
                                     Pctx0, Pctx1);
  k_pmerge<<<N, 64, 0, stream>>>(Pm, Ps, Pctx0, Pctx1, enc, pv_w2, pv_b2, ctx_ln_g,
                                 ctx_ln_b, enc2);
  k_colsum<<<32, 256, 0, stream>>>(enc2, part);
  k_score<<<N, 64, 0, stream>>>(enc2, sh_w1, sh_b1, sh_w2, sh_b2, part, out);
}

// Round 9
// 107.833 us; speedup vs baseline: 3.4259x; 1.1148x over previous
//
#include <hip/hip_runtime.h>
#include <hip/hip_bf16.h>
#include <hip/hip_fp16.h>
#include <math.h>

#define N 1024
#define F 256
#define H 64

typedef __attribute__((ext_vector_type(8))) _Float16 f16x8;
typedef __attribute__((ext_vector_type(4))) unsigned int u32x4;
typedef __attribute__((ext_vector_type(4))) float f32x4;

__device__ __forceinline__ float wave_reduce_sum(float v) {
#pragma unroll
  for (int off = 32; off; off >>= 1) v += __shfl_xor(v, off, 64);
  return v;
}

__device__ __forceinline__ unsigned int hpack(float a, float b) {
  __half ha = __float2half(a), hb = __float2half(b);
  unsigned short ua = __builtin_bit_cast(unsigned short, ha);
  unsigned short ub = __builtin_bit_cast(unsigned short, hb);
  return (unsigned int)ua | ((unsigned int)ub << 16);
}

// packed |a-b| on 2xf16
__device__ __forceinline__ unsigned int absdiff2(unsigned int a, unsigned int b) {
  __half2 ah = __builtin_bit_cast(__half2, a);
  __half2 bh = __builtin_bit_cast(__half2, b);
  __half2 d = __hsub2(ah, bh);
  return __builtin_bit_cast(unsigned int, d) & 0x7FFF7FFFu;
}

// ---------------- FUSED input_proj + qkv: Linear->LN->ReLU->Linear->ReLU->qkv proj
__global__ void k_input_qkv(const float* __restrict__ feat,
                            const float* __restrict__ w1, const float* __restrict__ b1,
                            const float* __restrict__ lng, const float* __restrict__ lnb,
                            const float* __restrict__ w2, const float* __restrict__ b2,
                            const float* __restrict__ aw, const float* __restrict__ abias,
                            float* __restrict__ h, float* __restrict__ Qh,
                            float* __restrict__ Kh, float* __restrict__ Vh) {
  const int row = blockIdx.x;
  const int lane = threadIdx.x;  // 0..63
  __shared__ float frow[F];
#pragma unroll
  for (int c = 0; c < 4; ++c) frow[c * 64 + lane] = feat[row * F + c * 64 + lane];
  __syncthreads();
  float acc = b1[lane];
#pragma unroll 8
  for (int k = 0; k < F; ++k) acc += frow[k] * w1[k * H + lane];
  float mu = wave_reduce_sum(acc) * (1.f / 64.f);
  float d = acc - mu;
  float var = wave_reduce_sum(d * d) * (1.f / 64.f);
  float y = d * rsqrtf(var + 1e-5f) * lng[lane] + lnb[lane];
  y = fmaxf(y, 0.f);
  __shared__ float yrow[H];
  yrow[lane] = y;
  __syncthreads();
  float acc2 = b2[lane];
#pragma unroll 8
  for (int k = 0; k < H; ++k) acc2 += yrow[k] * w2[k * H + lane];
  float hv = fmaxf(acc2, 0.f);
  h[row * H + lane] = hv;
  __shared__ float hrow[H];
  hrow[lane] = hv;
  __syncthreads();
  float a0 = abias[lane], a1 = abias[64 + lane], a2 = abias[128 + lane];
#pragma unroll 8
  for (int k = 0; k < H; ++k) {
    float hk = hrow[k];
    a0 += hk * aw[k * 192 + lane];
    a1 += hk * aw[k * 192 + 64 + lane];
    a2 += hk * aw[k * 192 + 128 + lane];
  }
  const int base = (lane >> 4) * (N * 16) + row * 16 + (lane & 15);
  Qh[base] = a0;
  Kh[base] = a1;
  Vh[base] = a2;
}

// ---------------- attention v3: 4 q-rows x 64 j-slots per block; wave owns one q-row.
__global__ __launch_bounds__(256) void k_attn2(const float* __restrict__ Qh,
                                               const float* __restrict__ Kh,
                                               const float* __restrict__ Vh,
                                               float* __restrict__ o) {
  const int head = blockIdx.x >> 8;
  const int i0 = (blockIdx.x & 255) * 4;
  const int tid = threadIdx.x;
  const int q2 = tid >> 6, js = tid & 63;
  const int i = i0 + q2;

  const float* qp = Qh + head * (N * 16) + i * 16;
  const float4 q0 = *(const float4*)(qp);
  const float4 q1 = *(const float4*)(qp + 4);
  const float4 q2v = *(const float4*)(qp + 8);
  const float4 q3 = *(const float4*)(qp + 12);
  const float* kb = Kh + head * (N * 16);
  const float* vb = Vh + head * (N * 16);

  float m = -3.0e38f, s = 0.f;
  float4 c0 = {0, 0, 0, 0}, c1 = {0, 0, 0, 0}, c2 = {0, 0, 0, 0}, c3 = {0, 0, 0, 0};

  int j = js;
  const float* kp = kb + j * 16;
  const float* vp = vb + j * 16;
  float4 k0 = *(const float4*)(kp), k1 = *(const float4*)(kp + 4);
  float4 k2 = *(const float4*)(kp + 8), k3 = *(const float4*)(kp + 12);
  float4 v0 = *(const float4*)(vp), v1 = *(const float4*)(vp + 4);
  float4 v2 = *(const float4*)(vp + 8), v3 = *(const float4*)(vp + 12);

#pragma unroll 1
  for (int t = 0; t < 16; ++t) {
    const int jn = (j + 64) & (N - 1);  // last-iter wrap: in-bounds, result unused
    const float* kpn = kb + jn * 16;
    const float* vpn = vb + jn * 16;
    float4 nk0 = *(const float4*)(kpn), nk1 = *(const float4*)(kpn + 4);
    float4 nk2 = *(const float4*)(kpn + 8), nk3 = *(const float4*)(kpn + 12);
    float4 nv0 = *(const float4*)(vpn), nv1 = *(const float4*)(vpn + 4);
    float4 nv2 = *(const float4*)(vpn + 8), nv3 = *(const float4*)(vpn + 12);

    float sc = q0.x * k0.x + q0.y * k0.y + q0.z * k0.z + q0.w * k0.w;
    sc += q1.x * k1.x + q1.y * k1.y + q1.z * k1.z + q1.w * k1.w;
    sc += q2v.x * k2.x + q2v.y * k2.y + q2v.z * k2.z + q2v.w * k2.w;
    sc += q3.x * k3.x + q3.y * k3.y + q3.z * k3.z + q3.w * k3.w;
    sc *= 0.25f;  // 1/sqrt(16)

    float mn = fmaxf(m, sc);
    float cc = __expf(m - mn);
    float p = __expf(sc - mn);
    s = s * cc + p;
    m = mn;
    c0.x = c0.x * cc + p * v0.x; c0.y = c0.y * cc + p * v0.y;
    c0.z = c0.z * cc + p * v0.z; c0.w = c0.w * cc + p * v0.w;
    c1.x = c1.x * cc + p * v1.x; c1.y = c1.y * cc + p * v1.y;
    c1.z = c1.z * cc + p * v1.z; c1.w = c1.w * cc + p * v1.w;
    c2.x = c2.x * cc + p * v2.x; c2.y = c2.y * cc + p * v2.y;
    c2.z = c2.z * cc + p * v2.z; c2.w = c2.w * cc + p * v2.w;
    c3.x = c3.x * cc + p * v3.x; c3.y = c3.y * cc + p * v3.y;
    c3.z = c3.z * cc + p * v3.z; c3.w = c3.w * cc + p * v3.w;

    k0 = nk0; k1 = nk1; k2 = nk2; k3 = nk3;
    v0 = nv0; v1 = nv1; v2 = nv2; v3 = nv3;
    j = jn;
  }

  float M = m, S = s;
#pragma unroll
  for (int off = 32; off; off >>= 1) {
    float Mo = __shfl_xor(M, off, 64);
    float So = __shfl_xor(S, off, 64);
    float Mn = fmaxf(M, Mo);
    S = S * __expf(M - Mn) + So * __expf(Mo - Mn);
    M = Mn;
  }
  const float wgt = __expf(m - M) / S;

  __shared__ float lds[4][64][17];
  float* lp = &lds[q2][js][0];
  lp[0] = c0.x * wgt;  lp[1] = c0.y * wgt;  lp[2] = c0.z * wgt;  lp[3] = c0.w * wgt;
  lp[4] = c1.x * wgt;  lp[5] = c1.y * wgt;  lp[6] = c1.z * wgt;  lp[7] = c1.w * wgt;
  lp[8] = c2.x * wgt;  lp[9] = c2.y * wgt;  lp[10] = c2.z * wgt; lp[11] = c2.w * wgt;
  lp[12] = c3.x * wgt; lp[13] = c3.y * wgt; lp[14] = c3.z * wgt; lp[15] = c3.w * wgt;
  __syncthreads();

  if (tid < 64) {
    const int q = tid >> 4, d = tid & 15;
    float sum = 0.f;
#pragma unroll
    for (int k = 0; k < 64; ++k) sum += lds[q][k][d];
    o[(i0 + q) * H + head * 16 + d] = sum;
  }
}

// ---------------- attn out proj + residual + LN -> enc
__global__ void k_attn_out(const float* __restrict__ o, const float* __restrict__ w,
                           const float* __restrict__ b, const float* __restrict__ h,
                           const float* __restrict__ lng, const float* __restrict__ lnb,
                           float* __restrict__ enc) {
  const int row = blockIdx.x;
  const int lane = threadIdx.x;
  __shared__ float orow[H];
  orow[lane] = o[row * H + lane];
  __syncthreads();
  float a = b[lane];
#pragma unroll 8
  for (int k = 0; k < H; ++k) a += orow[k] * w[k * H + lane];
  float x = h[row * H + lane] + a;
  float mu = wave_reduce_sum(x) * (1.f / 64.f);
  float d = x - mu;
  float var = wave_reduce_sum(d * d) * (1.f / 64.f);
  enc[row * H + lane] = d * rsqrtf(var + 1e-5f) * lng[lane] + lnb[lane];
}

// ---------------- MERGED prep: blocks 0..15 = combos; blocks 16..19 = W4^T f16 MFMA frags
__global__ __launch_bounds__(256) void k_prep(const float* __restrict__ pg1,
                                              const float* __restrict__ pv1,
                                              float* __restrict__ WgA, float* __restrict__ WgB,
                                              float* __restrict__ WvA, float* __restrict__ WvB,
                                              unsigned int* __restrict__ WF) {
  const int blk = blockIdx.x;
  if (blk < 16) {
    int idx = blk * 256 + threadIdx.x;  // 0..4095 == k*64+l
    float g1 = pg1[idx];
    float g2 = pg1[4096 + idx];
    float g3 = pg1[8192 + idx];
    WgA[idx] = g1 + g3;
    WgB[idx] = g2 - g3;
    float v1 = pv1[idx];
    float v2 = pv1[4096 + idx];
    float v3 = pv1[8192 + idx];
    WvA[idx] = v1 + v3;
    WvB[idx] = v2 - v3;
  } else {
    const int sub = threadIdx.x >> 6;
    const int lane = threadIdx.x & 63;
    const int b = (blk - 16) * 4 + sub;  // 0..15 = mat*8 + ks*4 + Mt
    const float* W = (b & 8) ? pv1 : pg1;
    const int Mt = b & 3;
    const int ks = (b >> 2) & 1;
    const int l = Mt * 16 + (lane & 15);
    const int kb = 192 + ks * 32 + (lane >> 4) * 8;  // |diff| block = rows 192..255
    uint4 o;
    o.x = hpack(W[(kb + 0) * H + l], W[(kb + 1) * H + l]);
    o.y = hpack(W[(kb + 2) * H + l], W[(kb + 3) * H + l]);
    o.z = hpack(W[(kb + 4) * H + l], W[(kb + 5) * H + l]);
    o.w = hpack(W[(kb + 6) * H + l], W[(kb + 7) * H + l]);
    ((uint4*)WF)[b * 64 + lane] = o;
  }
}

// ---------------- per-row projections + packed-f16 enc copy
__global__ void k_ab(const float* __restrict__ enc, const float* __restrict__ WgA,
                     const float* __restrict__ WgB, const float* __restrict__ WvA,
                     const float* __restrict__ WvB, const float* __restrict__ pg_b1,
                     const float* __restrict__ pv_b1, float* __restrict__ Ag,
                     float* __restrict__ Av, float* __restrict__ Pg,
                     float* __restrict__ Pv, unsigned int* __restrict__ encH) {
  const int row = blockIdx.x;
  const int lane = threadIdx.x;
  __shared__ float erow[H];
  erow[lane] = enc[row * H + lane];
  __syncthreads();
  if (lane < 32) encH[row * 32 + lane] = hpack(erow[2 * lane], erow[2 * lane + 1]);
  float ag = pg_b1[lane], bg = 0.f, av = pv_b1[lane], bv = 0.f;
#pragma unroll 4
  for (int k = 0; k < H; ++k) {
    float e = erow[k];
    ag += e * WgA[k * H + lane];
    bg += e * WgB[k * H + lane];
    av += e * WvA[k * H + lane];
    bv += e * WvB[k * H + lane];
  }
  Ag[row * H + lane] = ag;
  Av[row * H + lane] = av;
  int idx = (((row >> 4) * 4 + (lane >> 4)) * 4 + ((lane >> 2) & 3)) * 64 +
            (row & 15) * 4 + (lane & 3);
  Pg[idx] = bg;
  Pv[idx] = bv;
}

// ---------------- PAIR PARTIAL (f16 MFMA): 2 blocks per i (j-halves), 2 waves per block.
// v4: packed-f16 diff (v_pk_sub + and-abs replaces the bf16 cvt storm), halved ej bytes.
__global__ __launch_bounds__(128) void k_pairp(
    const unsigned int* __restrict__ encH, const float* __restrict__ Ag,
    const float* __restrict__ Av, const unsigned int* __restrict__ WF,
    const float* __restrict__ Pg, const float* __restrict__ Pv,
    const float* __restrict__ pg_w2, const float* __restrict__ pg_b2,
    float* __restrict__ Pm, float* __restrict__ Ps,
    float* __restrict__ Pctx0, float* __restrict__ Pctx1) {
  const int bid = blockIdx.x;
  const int i = bid & (N - 1);
  const int half = bid >> 10;
  const int tid = threadIdx.x;
  const int lane = tid & 63;
  const int w = tid >> 6;  // 0/1: quarter within this half
  const int l15 = lane & 15, g4 = lane >> 4;
  const float LOG2E = 1.44269504088896f;

  f16x8 wg[2][4], wv[2][4];
  const uint4* WF4 = (const uint4*)WF;
#pragma unroll
  for (int ks = 0; ks < 2; ++ks)
#pragma unroll
    for (int Mt = 0; Mt < 4; ++Mt) {
      wg[ks][Mt] = __builtin_bit_cast(f16x8, WF4[(ks * 4 + Mt) * 64 + lane]);
      wv[ks][Mt] = __builtin_bit_cast(f16x8, WF4[((2 + ks) * 4 + Mt) * 64 + lane]);
    }

  // ei: packed f16, 8 u32 (16 k-values) per lane
  const uint4* eH = (const uint4*)encH + (size_t)i * 8;
  const uint4 eiL = eH[g4];
  const uint4 eiU = eH[4 + g4];

  f32x4 agv[4], avv[4];
  float4 w2s[4];
#pragma unroll
  for (int Mt = 0; Mt < 4; ++Mt) {
    float4 t = *(const float4*)(Ag + i * H + Mt * 16 + g4 * 4);
    agv[Mt] = f32x4{t.x, t.y, t.z, t.w};
    float4 u = *(const float4*)(Av + i * H + Mt * 16 + g4 * 4);
    avv[Mt] = f32x4{u.x, u.y, u.z, u.w};
    float4 ww = *(const float4*)(pg_w2 + Mt * 16 + g4 * 4);
    w2s[Mt] = make_float4(ww.x * LOG2E, ww.y * LOG2E, ww.z * LOG2E, ww.w * LOG2E);
  }
  const float b2g = pg_b2[0] * LOG2E;

  float m = -3.0e38f, s = 0.f;
  float ctx[16];
#pragma unroll
  for (int e = 0; e < 16; ++e) ctx[e] = 0.f;

  const int jbase = half * 512 + w * 256;
  const uint4* ejp = (const uint4*)encH + (size_t)(jbase + l15) * 8;
  uint4 na = ejp[g4];
  uint4 nc = ejp[4 + g4];

#pragma unroll 1
  for (int t = 0; t < 16; ++t) {
    const int j0 = jbase + t * 16;
    const int pbase = ((j0 >> 4) * 16 + g4) * 64 + l15 * 4;
    // gate-side B terms (needed right after cg MFMAs)
    float4 pg0 = *(const float4*)(Pg + pbase);
    float4 pg1 = *(const float4*)(Pg + pbase + 256);
    float4 pg2 = *(const float4*)(Pg + pbase + 512);
    float4 pg3 = *(const float4*)(Pg + pbase + 768);

    // B fragments: |ei - ej| in packed f16 (8 pk_sub + 8 and)
    u32x4 t0 = {absdiff2(eiL.x, na.x), absdiff2(eiL.y, na.y),
                absdiff2(eiL.z, na.z), absdiff2(eiL.w, na.w)};
    u32x4 t1 = {absdiff2(eiU.x, nc.x), absdiff2(eiU.y, nc.y),
                absdiff2(eiU.z, nc.z), absdiff2(eiU.w, nc.w)};
    f16x8 b0 = __builtin_bit_cast(f16x8, t0);
    f16x8 b1 = __builtin_bit_cast(f16x8, t1);
    // prefetch next tile's ej (last-iter overread stays inside d_ws: unused)
    ejp += 16 * 8;
    na = ejp[g4];
    nc = ejp[4 + g4];

    f32x4 cg[4], cv[4];
#pragma unroll
    for (int Mt = 0; Mt < 4; ++Mt) {
      cg[Mt] = __builtin_amdgcn_mfma_f32_16x16x32_f16(wg[0][Mt], b0, agv[Mt], 0, 0, 0);
      cg[Mt] = __builtin_amdgcn_mfma_f32_16x16x32_f16(wg[1][Mt], b1, cg[Mt], 0, 0, 0);
      cv[Mt] = __builtin_amdgcn_mfma_f32_16x16x32_f16(wv[0][Mt], b0, avv[Mt], 0, 0, 0);
      cv[Mt] = __builtin_amdgcn_mfma_f32_16x16x32_f16(wv[1][Mt], b1, cv[Mt], 0, 0, 0);
    }

    // val-side B terms: issue now, consumed after gate epilogue (latency hidden)
    float4 pv0 = *(const float4*)(Pv + pbase);
    float4 pv1 = *(const float4*)(Pv + pbase + 256);
    float4 pv2 = *(const float4*)(Pv + pbase + 512);
    float4 pv3 = *(const float4*)(Pv + pbase + 768);

    // gate (log2 domain): 4 independent fma chains, then pairwise sum
    float ga = fmaxf(cg[0][0] + pg0.x, 0.f) * w2s[0].x;
    float gb = fmaxf(cg[0][1] + pg0.y, 0.f) * w2s[0].y;
    float gc = fmaxf(cg[0][2] + pg0.z, 0.f) * w2s[0].z;
    float gd = fmaxf(cg[0][3] + pg0.w, 0.f) * w2s[0].w;
    ga = fmaf(fmaxf(cg[1][0] + pg1.x, 0.f), w2s[1].x, ga);
    gb = fmaf(fmaxf(cg[1][1] + pg1.y, 0.f), w2s[1].y, gb);
    gc = fmaf(fmaxf(cg[1][2] + pg1.z, 0.f), w2s[1].z, gc);
    gd = fmaf(fmaxf(cg[1][3] + pg1.w, 0.f), w2s[1].w, gd);
    ga = fmaf(fmaxf(cg[2][0] + pg2.x, 0.f), w2s[2].x, ga);
    gb = fmaf(fmaxf(cg[2][1] + pg2.y, 0.f), w2s[2].y, gb);
    gc = fmaf(fmaxf(cg[2][2] + pg2.z, 0.f), w2s[2].z, gc);
    gd = fmaf(fmaxf(cg[2][3] + pg2.w, 0.f), w2s[2].w, gd);
    ga = fmaf(fmaxf(cg[3][0] + pg3.x, 0.f), w2s[3].x, ga);
    gb = fmaf(fmaxf(cg[3][1] + pg3.y, 0.f), w2s[3].y, gb);
    gc = fmaf(fmaxf(cg[3][2] + pg3.z, 0.f), w2s[3].z, gc);
    gd = fmaf(fmaxf(cg[3][3] + pg3.w, 0.f), w2s[3].w, gd);
    float gate = (ga + gb) + (gc + gd);
    gate += __shfl_xor(gate, 16, 64);
    gate += __shfl_xor(gate, 32, 64);
    gate += b2g;
    if (j0 + l15 == i) gate = -3.0e38f;  // diagonal mask

    float p;
    if (__any(gate > m + 8.f)) {  // rescale only when some lane's max grew
      float mn = fmaxf(m, gate);
      float c = exp2f(m - mn);
      p = exp2f(gate - mn);
      s *= c;
      m = mn;
#pragma unroll
      for (int e = 0; e < 16; ++e) ctx[e] *= c;
    } else {
      p = exp2f(gate - m);  // bounded by 2^8
    }
    s += p;
    ctx[0]  = fmaf(p, fmaxf(cv[0][0] + pv0.x, 0.f), ctx[0]);
    ctx[1]  = fmaf(p, fmaxf(cv[0][1] + pv0.y, 0.f), ctx[1]);
    ctx[2]  = fmaf(p, fmaxf(cv[0][2] + pv0.z, 0.f), ctx[2]);
    ctx[3]  = fmaf(p, fmaxf(cv[0][3] + pv0.w, 0.f), ctx[3]);
    ctx[4]  = fmaf(p, fmaxf(cv[1][0] + pv1.x, 0.f), ctx[4]);
    ctx[5]  = fmaf(p, fmaxf(cv[1][1] + pv1.y, 0.f), ctx[5]);
    ctx[6]  = fmaf(p, fmaxf(cv[1][2] + pv1.z, 0.f), ctx[6]);
    ctx[7]  = fmaf(p, fmaxf(cv[1][3] + pv1.w, 0.f), ctx[7]);
    ctx[8]  = fmaf(p, fmaxf(cv[2][0] + pv2.x, 0.f), ctx[8]);
    ctx[9]  = fmaf(p, fmaxf(cv[2][1] + pv2.y, 0.f), ctx[9]);
    ctx[10] = fmaf(p, fmaxf(cv[2][2] + pv2.z, 0.f), ctx[10]);
    ctx[11] = fmaf(p, fmaxf(cv[2][3] + pv2.w, 0.f), ctx[11]);
    ctx[12] = fmaf(p, fmaxf(cv[3][0] + pv3.x, 0.f), ctx[12]);
    ctx[13] = fmaf(p, fmaxf(cv[3][1] + pv3.y, 0.f), ctx[13]);
    ctx[14] = fmaf(p, fmaxf(cv[3][2] + pv3.z, 0.f), ctx[14]);
    ctx[15] = fmaf(p, fmaxf(cv[3][3] + pv3.w, 0.f), ctx[15]);
  }

  // in-wave flash-merge across the 16 j-columns (xor butterfly over lane&15)
#pragma unroll
  for (int off = 1; off <= 8; off <<= 1) {
    float mo = __shfl_xor(m, off, 64);
    float so = __shfl_xor(s, off, 64);
    float M2 = fmaxf(m, mo);
    float ca = exp2f(m - M2);
    float cb = exp2f(mo - M2);
    s = s * ca + so * cb;
#pragma unroll
    for (int e = 0; e < 16; ++e) {
      float co = __shfl_xor(ctx[e], off, 64);
      ctx[e] = ctx[e] * ca + co * cb;
    }
    m = M2;
  }

  __shared__ float ctxs[2][64];
  __shared__ float mss[2][2];
  if (l15 == 0) {
#pragma unroll
    for (int Mt = 0; Mt < 4; ++Mt)
#pragma unroll
      for (int r = 0; r < 4; ++r) ctxs[w][Mt * 16 + g4 * 4 + r] = ctx[Mt * 4 + r];
  }
  if (lane == 0) {
    mss[w][0] = m;
    mss[w][1] = s;
  }
  __syncthreads();

  if (w == 0) {
    float m0 = mss[0][0], s0 = mss[0][1], m1 = mss[1][0], s1 = mss[1][1];
    float M = fmaxf(m0, m1);
    float e0 = exp2f(m0 - M), e1 = exp2f(m1 - M);
    float S = s0 * e0 + s1 * e1;
    float cm = ctxs[0][lane] * e0 + ctxs[1][lane] * e1;  // unnormalized
    float* dst = half ? Pctx1 : Pctx0;
    dst[i * H + lane] = cm;
    if (lane == 0) {
      Pm[bid] = M;
      Ps[bid] = S;
    }
  }
}

// ---------------- merge two j-half partials + pv_w2 matvec + residual + LN -> enc2
__global__ void k_pmerge(const float* __restrict__ Pm, const float* __restrict__ Ps,
                         const float* __restrict__ Pctx0, const float* __restrict__ Pctx1,
                         const float* __restrict__ enc, const float* __restrict__ pv_w2,
                         const float* __restrict__ pv_b2, const float* __restrict__ lng,
                         const float* __restrict__ lnb, float* __restrict__ enc2) {
  const int i = blockIdx.x;
  const int lane = threadIdx.x;
  float m0 = Pm[i], s0 = Ps[i], m1 = Pm[N + i], s1 = Ps[N + i];
  float c0 = Pctx0[i * H + lane];
  float c1 = Pctx1[i * H + lane];  // aliases enc2[i*H+lane]; read-before-write below
  float M = fmaxf(m0, m1);
  float e0 = exp2f(m0 - M), e1 = exp2f(m1 - M);
  float S = s0 * e0 + s1 * e1;
  float cp = (c0 * e0 + c1 * e1) / S;
  float pc = pv_b2[lane];
#pragma unroll 8
  for (int k = 0; k < 64; ++k) pc += __shfl(cp, k, 64) * pv_w2[k * H + lane];
  float x = enc[i * H + lane] + pc;
  float mu = wave_reduce_sum(x) * (1.f / 64.f);
  float dd = x - mu;
  float var = wave_reduce_sum(dd * dd) * (1.f / 64.f);
  enc2[i * H + lane] = dd * rsqrtf(var + 1e-5f) * lng[lane] + lnb[lane];
}

// ---------------- column-sum stage 1: 32 blocks x 32 rows each
__global__ __launch_bounds__(256) void k_colsum(const float* __restrict__ enc2,
                                                float* __restrict__ part) {
  const int b = blockIdx.x;
  const int lane = threadIdx.x & 63, grp = threadIdx.x >> 6;
  const float* p = enc2 + (b * 32 + grp) * H + lane;
  float s = 0.f;
#pragma unroll
  for (int r = 0; r < 8; ++r) s += p[r * 4 * H];
  __shared__ float sh[4][64];
  sh[grp][lane] = s;
  __syncthreads();
  if (grp == 0) part[b * 64 + lane] = sh[0][lane] + sh[1][lane] + sh[2][lane] + sh[3][lane];
}

// ---------------- score head (graph-mean base folded in per-block)
__global__ void k_score(const float* __restrict__ enc2, const float* __restrict__ sh_w1,
                        const float* __restrict__ sh_b1, const float* __restrict__ sh_w2,
                        const float* __restrict__ sh_b2, const float* __restrict__ part,
                        float* __restrict__ out) {
  const int row = blockIdx.x;
  const int lane = threadIdx.x;
  __shared__ float erow[H];
  erow[lane] = enc2[row * H + lane];
  __syncthreads();
  float g = 0.f;
#pragma unroll
  for (int p = 0; p < 32; ++p) g += part[p * 64 + lane];
  g *= (1.f / N);
  float t = sh_b1[lane];
#pragma unroll 8
  for (int k = 0; k < 64; ++k) {
    t += erow[k] * sh_w1[k * H + lane];
    t += __shfl(g, k, 64) * sh_w1[(64 + k) * H + lane];
  }
  t = fmaxf(t, 0.f);
  float prt = t * sh_w2[lane];
  float sum = wave_reduce_sum(prt);
  if (lane == 0) out[row] = sum + sh_b2[0];
}

extern "C" void kernel_launch(void* const* d_in, const int* in_sizes, int n_in,
                              void* d_out, int out_size, void* d_ws, size_t ws_size,
                              hipStream_t stream) {
  const float* feat = (const float*)d_in[0];
  const float* ip_w1 = (const float*)d_in[1];
  const float* ip_b1 = (const float*)d_in[2];
  const float* ip_ln_g = (const float*)d_in[3];
  const float* ip_ln_b = (const float*)d_in[4];
  const float* ip_w2 = (const float*)d_in[5];
  const float* ip_b2 = (const float*)d_in[6];
  const float* attn_in_w = (const float*)d_in[7];
  const float* attn_in_b = (const float*)d_in[8];
  const float* attn_out_w = (const float*)d_in[9];
  const float* attn_out_b = (const float*)d_in[10];
  const float* attn_ln_g = (const float*)d_in[11];
  const float* attn_ln_b = (const float*)d_in[12];
  const float* pg_w1 = (const float*)d_in[13];
  const float* pg_b1 = (const float*)d_in[14];
  const float* pg_w2 = (const float*)d_in[15];
  const float* pg_b2 = (const float*)d_in[16];
  const float* pv_w1 = (const float*)d_in[17];
  const float* pv_b1 = (const float*)d_in[18];
  const float* pv_w2 = (const float*)d_in[19];
  const float* pv_b2 = (const float*)d_in[20];
  const float* ctx_ln_g = (const float*)d_in[21];
  const float* ctx_ln_b = (const float*)d_in[22];
  const float* sh_w1 = (const float*)d_in[23];
  const float* sh_b1 = (const float*)d_in[24];
  const float* sh_w2 = (const float*)d_in[25];
  const float* sh_b2 = (const float*)d_in[26];

  float* ws = (float*)d_ws;
  float* h = ws;                        // 0      .. 65536   (dead after k_attn_out)
  float* Qh = ws + 65536;               // 65536  .. 131072
  float* Kh = ws + 131072;              // 131072 .. 196608
  float* Vh = ws + 196608;              // 196608 .. 262144
  float* o = ws + 262144;               // 262144 .. 327680
  float* enc = ws + 327680;             // 327680 .. 393216
  float* enc2 = ws + 393216;            // 393216 .. 458752
  float* Pg = ws + 65536;               // reuse Qh (64K floats)
  float* Pv = ws + 131072;              // reuse Kh (64K floats)
  float* Ag = ws + 196608;              // reuse Vh
  float* Av = ws + 262144;              // reuse o
  float* Pctx0 = ws;                    // reuse h (64K floats)
  float* Pctx1 = enc2;                  // merge reads partial then overwrites same slot
  float* WgA = ws + 458752;             // 4096 each
  float* WgB = ws + 462848;
  float* WvA = ws + 466944;
  float* WvB = ws + 471040;
  unsigned int* WF = (unsigned int*)(ws + 475136);  // 4096 u32
  float* part = ws + 479232;            // 2048
  float* Pm = ws + 481280;              // 2048
  float* Ps = ws + 483328;              // 2048
  unsigned int* encH = (unsigned int*)(ws + 485376);  // 32768 u32 (f16-packed enc)
  float* out = (float*)d_out;

  k_input_qkv<<<N, 64, 0, stream>>>(feat, ip_w1, ip_b1, ip_ln_g, ip_ln_b, ip_w2, ip_b2,
                                    attn_in_w, attn_in_b, h, Qh, Kh, Vh);
  k_attn2<<<1024, 256, 0, stream>>>(Qh, Kh, Vh, o);
  k_attn_out<<<N, 64, 0, stream>>>(o, attn_out_w, attn_out_b, h, attn_ln_g, attn_ln_b, enc);
  k_prep<<<20, 256, 0, stream>>>(pg_w1, pv_w1, WgA, WgB, WvA, WvB, WF);
  k_ab<<<N, 64, 0, stream>>>(enc, WgA, WgB, WvA, WvB, pg_b1, pv_b1, Ag, Av, Pg, Pv, encH);
  k_pairp<<<2 * N, 128, 0, stream>>>(encH, Ag, Av, WF, Pg, Pv, pg_w2, pg_b2, Pm, Ps,
                                     Pctx0, Pctx1);
  k_pmerge<<<N, 64, 0, stream>>>(Pm, Ps, Pctx0, Pctx1, enc, pv_w2, pv_b2, ctx_ln_g,
                                 ctx_ln_b, enc2);
  k_colsum<<<32, 256, 0, stream>>>(enc2, part);
  k_score<<<N, 64, 0, stream>>>(enc2, sh_w1, sh_b1, sh_w2, sh_b2, part, out);
}